// Round 2
// baseline (835.471 us; speedup 1.0000x reference)
//
#include <hip/hip_runtime.h>
#include <hip/hip_bf16.h>
#include <math.h>

#define N_NODESC 50000
#define N_EDGESC 500000
#define E_TOT    (N_EDGESC + N_NODESC)   // 550000 (self-loops appended)
#define IN_CH 128
#define HID 32
#define HEADS 4
#define HC (HEADS*HID)    // 128
#define OUT_CH 64
#define NEG_SLOPE 0.2f

// ---- order-preserving float <-> uint mapping for atomic max ----
__device__ __forceinline__ unsigned fmapu(float f){
  unsigned u = __float_as_uint(f);
  return (u & 0x80000000u) ? ~u : (u | 0x80000000u);
}
__device__ __forceinline__ float unmapu(unsigned u){
  unsigned v = (u & 0x80000000u) ? (u & 0x7FFFFFFFu) : ~u;
  return __uint_as_float(v);
}
#define SMAX_INIT_U 0x007FFFFFu   // fmapu(-inf) = ~0xFF800000

__device__ __forceinline__ void edge_sd(const int* __restrict__ ei, int e, int& s, int& d){
  if (e < N_EDGESC){ s = ei[e]; d = ei[N_EDGESC + e]; }
  else { s = e - N_EDGESC; d = s; }
}

// ---------------- init ----------------
__global__ void k_init(float* __restrict__ out1, float* __restrict__ out2,
                       unsigned* __restrict__ smax1, float* __restrict__ den1,
                       unsigned* __restrict__ smax2, float* __restrict__ den2){
  int i = blockIdx.x*blockDim.x + threadIdx.x;
  if (i < N_NODESC*HC)      out1[i] = 0.f;
  if (i < N_NODESC*OUT_CH)  out2[i] = 0.f;
  if (i < N_NODESC*HEADS){  smax1[i] = SMAX_INIT_U; den1[i] = 0.f; }
  if (i < N_NODESC){        smax2[i] = SMAX_INIT_U; den2[i] = 0.f; }
}

// ---------------- layer 1 GEMM: xl1 = x@W1l, xr1 = x@W1r ----------------
#define G1_NPB 8
__global__ void k_gemm1(const float* __restrict__ x, const float* __restrict__ Wl,
                        const float* __restrict__ Wr, float* __restrict__ xl,
                        float* __restrict__ xr){
  __shared__ float xs[G1_NPB][IN_CH];
  int t = threadIdx.x;               // 256
  int node0 = blockIdx.x * G1_NPB;
  for (int i = t; i < G1_NPB*IN_CH; i += 256){
    int r = i >> 7, c = i & 127;
    xs[r][c] = x[(size_t)(node0 + r)*IN_CH + c];
  }
  __syncthreads();
  int col = t & 127;
  const float* __restrict__ W = (t < 128) ? Wl : Wr;
  float* __restrict__ O = (t < 128) ? xl : xr;
  float acc[G1_NPB];
  #pragma unroll
  for (int i=0;i<G1_NPB;i++) acc[i]=0.f;
  for (int k=0;k<IN_CH;k++){
    float w = W[k*HC + col];
    #pragma unroll
    for (int i=0;i<G1_NPB;i++) acc[i] += xs[i][k] * w;
  }
  #pragma unroll
  for (int i=0;i<G1_NPB;i++) O[(size_t)(node0+i)*HC + col] = acc[i];
}

// ---------------- layer 1 scores + segment max ----------------
__global__ void k_score1(const int* __restrict__ ei, const float* __restrict__ xl,
                         const float* __restrict__ xr, const float* __restrict__ att,
                         float* __restrict__ score, unsigned* __restrict__ smax){
  int t = threadIdx.x;
  int lane = t & 31;
  int e = blockIdx.x * 8 + (t >> 5);
  if (e >= E_TOT) return;
  int s, d; edge_sd(ei, e, s, d);
  const float* __restrict__ xls = xl + (size_t)s * HC;
  const float* __restrict__ xrd = xr + (size_t)d * HC;
  float p[HEADS];
  #pragma unroll
  for (int h=0; h<HEADS; h++){
    int c = h*HID + lane;
    float v = xls[c] + xrd[c];
    v = (v > 0.f) ? v : NEG_SLOPE * v;
    p[h] = v * att[c];
  }
  #pragma unroll
  for (int off=16; off>=1; off>>=1){
    #pragma unroll
    for (int h=0;h<HEADS;h++) p[h] += __shfl_xor(p[h], off);
  }
  if (lane == 0){
    #pragma unroll
    for (int h=0;h<HEADS;h++){
      score[(size_t)e*HEADS + h] = p[h];
      atomicMax(&smax[d*HEADS + h], fmapu(p[h]));
    }
  }
}

// ---------------- layer 1 exp + denom ----------------
__global__ void k_expsum1(const int* __restrict__ ei, float* __restrict__ score,
                          const unsigned* __restrict__ smax, float* __restrict__ den){
  int i = blockIdx.x*blockDim.x + threadIdx.x;
  if (i >= E_TOT*HEADS) return;
  int e = i >> 2, h = i & 3;
  int d = (e < N_EDGESC) ? ei[N_EDGESC + e] : (e - N_EDGESC);
  float p = expf(score[i] - unmapu(smax[d*HEADS + h]));
  score[i] = p;
  atomicAdd(&den[d*HEADS + h], p);
}

// ---------------- layer 1 aggregate ----------------
__global__ void k_agg1(const int* __restrict__ ei, const float* __restrict__ score,
                       const float* __restrict__ den, const float* __restrict__ xl,
                       float* __restrict__ out){
  int t = threadIdx.x;
  int c = t & 127;
  int e = blockIdx.x * 2 + (t >> 7);
  if (e >= E_TOT) return;
  int s, d; edge_sd(ei, e, s, d);
  int h = c >> 5;
  float alpha = score[(size_t)e*HEADS + h] / (den[d*HEADS + h] + 1e-16f);
  atomicAdd(&out[(size_t)d*HC + c], alpha * xl[(size_t)s*HC + c]);
}

// ---------------- bias + ELU ----------------
__global__ void k_elu(float* __restrict__ h, const float* __restrict__ b1){
  int i = blockIdx.x*blockDim.x + threadIdx.x;
  if (i >= N_NODESC*HC) return;
  float v = h[i] + b1[i & 127];
  h[i] = (v > 0.f) ? v : (expf(v) - 1.f);
}

// ---------------- layer 2 GEMM: xl2 = h@W2l, xr2 = h@W2r ----------------
#define G2_NPB 8
__global__ void k_gemm2(const float* __restrict__ h, const float* __restrict__ Wl,
                        const float* __restrict__ Wr, float* __restrict__ xl,
                        float* __restrict__ xr){
  __shared__ float hs[G2_NPB][HC];
  int t = threadIdx.x;               // 128
  int node0 = blockIdx.x * G2_NPB;
  for (int i = t; i < G2_NPB*HC; i += 128){
    int r = i >> 7, c = i & 127;
    hs[r][c] = h[(size_t)(node0 + r)*HC + c];
  }
  __syncthreads();
  int col = t & 63;
  const float* __restrict__ W = (t < 64) ? Wl : Wr;
  float* __restrict__ O = (t < 64) ? xl : xr;
  float acc[G2_NPB];
  #pragma unroll
  for (int i=0;i<G2_NPB;i++) acc[i]=0.f;
  for (int k=0;k<HC;k++){
    float w = W[k*OUT_CH + col];
    #pragma unroll
    for (int i=0;i<G2_NPB;i++) acc[i] += hs[i][k] * w;
  }
  #pragma unroll
  for (int i=0;i<G2_NPB;i++) O[(size_t)(node0+i)*OUT_CH + col] = acc[i];
}

// ---------------- layer 2 scores + segment max (heads=1, 64 ch) ----------------
__global__ void k_score2(const int* __restrict__ ei, const float* __restrict__ xl,
                         const float* __restrict__ xr, const float* __restrict__ att,
                         float* __restrict__ score, unsigned* __restrict__ smax){
  int t = threadIdx.x;
  int lane = t & 63;
  int e = blockIdx.x * 4 + (t >> 6);
  if (e >= E_TOT) return;
  int s, d; edge_sd(ei, e, s, d);
  float v = xl[(size_t)s*OUT_CH + lane] + xr[(size_t)d*OUT_CH + lane];
  v = (v > 0.f) ? v : NEG_SLOPE * v;
  float p = v * att[lane];
  #pragma unroll
  for (int off=32; off>=1; off>>=1) p += __shfl_xor(p, off);
  if (lane == 0){
    score[e] = p;
    atomicMax(&smax[d], fmapu(p));
  }
}

// ---------------- layer 2 exp + denom ----------------
__global__ void k_expsum2(const int* __restrict__ ei, float* __restrict__ score,
                          const unsigned* __restrict__ smax, float* __restrict__ den){
  int e = blockIdx.x*blockDim.x + threadIdx.x;
  if (e >= E_TOT) return;
  int d = (e < N_EDGESC) ? ei[N_EDGESC + e] : (e - N_EDGESC);
  float p = expf(score[e] - unmapu(smax[d]));
  score[e] = p;
  atomicAdd(&den[d], p);
}

// ---------------- layer 2 aggregate ----------------
__global__ void k_agg2(const int* __restrict__ ei, const float* __restrict__ score,
                       const float* __restrict__ den, const float* __restrict__ xl,
                       float* __restrict__ out){
  int t = threadIdx.x;
  int c = t & 63;
  int e = blockIdx.x * 4 + (t >> 6);
  if (e >= E_TOT) return;
  int s, d; edge_sd(ei, e, s, d);
  float alpha = score[e] / (den[d] + 1e-16f);
  atomicAdd(&out[(size_t)d*OUT_CH + c], alpha * xl[(size_t)s*OUT_CH + c]);
}

// ---------------- final: bias add ----------------
__global__ void k_final(const float* __restrict__ out2, const float* __restrict__ b2,
                        float* __restrict__ out){
  int i = blockIdx.x*blockDim.x + threadIdx.x;
  if (i >= N_NODESC*OUT_CH) return;
  out[i] = out2[i] + b2[i & 63];
}

extern "C" void kernel_launch(void* const* d_in, const int* in_sizes, int n_in,
                              void* d_out, int out_size, void* d_ws, size_t ws_size,
                              hipStream_t stream) {
  const float* x    = (const float*)d_in[0];
  const int*   ei   = (const int*)d_in[1];
  const float* W1l  = (const float*)d_in[2];
  const float* W1r  = (const float*)d_in[3];
  const float* att1 = (const float*)d_in[4];
  const float* b1   = (const float*)d_in[5];
  const float* W2l  = (const float*)d_in[6];
  const float* W2r  = (const float*)d_in[7];
  const float* att2 = (const float*)d_in[8];
  const float* b2   = (const float*)d_in[9];
  float* out = (float*)d_out;

  // workspace layout (fp32 / u32)
  float* ws = (float*)d_ws;
  size_t off = 0;
  float* xl1   = ws + off; off += (size_t)N_NODESC*HC;
  float* xr1   = ws + off; off += (size_t)N_NODESC*HC;
  float* out1  = ws + off; off += (size_t)N_NODESC*HC;      // reused as h after ELU
  float* xl2   = ws + off; off += (size_t)N_NODESC*OUT_CH;
  float* xr2   = ws + off; off += (size_t)N_NODESC*OUT_CH;
  float* out2  = ws + off; off += (size_t)N_NODESC*OUT_CH;
  unsigned* smax1 = (unsigned*)(ws + off); off += (size_t)N_NODESC*HEADS;
  float* den1  = ws + off; off += (size_t)N_NODESC*HEADS;
  unsigned* smax2 = (unsigned*)(ws + off); off += (size_t)N_NODESC;
  float* den2  = ws + off; off += (size_t)N_NODESC;
  float* sc1   = ws + off; off += (size_t)E_TOT*HEADS;
  float* sc2   = ws + off; off += (size_t)E_TOT;

  k_init<<<(N_NODESC*HC + 255)/256, 256, 0, stream>>>(out1, out2, smax1, den1, smax2, den2);

  // layer 1
  k_gemm1<<<N_NODESC/G1_NPB, 256, 0, stream>>>(x, W1l, W1r, xl1, xr1);
  k_score1<<<(E_TOT + 7)/8, 256, 0, stream>>>(ei, xl1, xr1, att1, sc1, smax1);
  k_expsum1<<<(E_TOT*HEADS + 255)/256, 256, 0, stream>>>(ei, sc1, smax1, den1);
  k_agg1<<<(E_TOT + 1)/2, 256, 0, stream>>>(ei, sc1, den1, xl1, out1);
  k_elu<<<(N_NODESC*HC + 255)/256, 256, 0, stream>>>(out1, b1);

  // layer 2
  k_gemm2<<<N_NODESC/G2_NPB, 128, 0, stream>>>(out1, W2l, W2r, xl2, xr2);
  k_score2<<<(E_TOT + 3)/4, 256, 0, stream>>>(ei, xl2, xr2, att2, sc2, smax2);
  k_expsum2<<<(E_TOT + 255)/256, 256, 0, stream>>>(ei, sc2, smax2, den2);
  k_agg2<<<(E_TOT + 3)/4, 256, 0, stream>>>(ei, sc2, den2, xl2, out2);

  // epilogue
  k_final<<<(N_NODESC*OUT_CH + 255)/256, 256, 0, stream>>>(out2, b2, out);
}

// Round 3
// 380.967 us; speedup vs baseline: 2.1930x; 2.1930x over previous
//
#include <hip/hip_runtime.h>
#include <hip/hip_bf16.h>
#include <math.h>

#define N_NODESC 50000
#define N_EDGESC 500000
#define E_TOT    (N_EDGESC + N_NODESC)   // 550000 (self-loops appended)
#define IN_CH 128
#define HID 32
#define HEADS 4
#define HC (HEADS*HID)    // 128
#define OUT_CH 64
#define NEG_SLOPE 0.2f
#define NB_SCAN 196        // ceil(50000/256)

__device__ __forceinline__ void edge_sd(const int* __restrict__ ei, int e, int& s, int& d){
  if (e < N_EDGESC){ s = ei[e]; d = ei[N_EDGESC + e]; }
  else { s = e - N_EDGESC; d = s; }
}

// ---------------- CSR build ----------------
__global__ void k_zero_deg(int* __restrict__ deg){
  int i = blockIdx.x*blockDim.x + threadIdx.x;
  if (i < N_NODESC) deg[i] = 0;
}

__global__ void k_hist(const int* __restrict__ ei, int* __restrict__ deg){
  int e = blockIdx.x*blockDim.x + threadIdx.x;
  if (e >= E_TOT) return;
  int s, d; edge_sd(ei, e, s, d);
  atomicAdd(&deg[d], 1);
}

__global__ void k_scan_a(const int* __restrict__ deg, int* __restrict__ rs,
                         int* __restrict__ bsum){
  __shared__ int sh[256];
  int i = blockIdx.x*256 + threadIdx.x;
  int v = (i < N_NODESC) ? deg[i] : 0;
  sh[threadIdx.x] = v;
  __syncthreads();
  for (int off=1; off<256; off<<=1){
    int t = (threadIdx.x >= off) ? sh[threadIdx.x-off] : 0;
    __syncthreads();
    sh[threadIdx.x] += t;
    __syncthreads();
  }
  if (i < N_NODESC) rs[i] = sh[threadIdx.x] - v;       // exclusive within block
  if (threadIdx.x == 255) bsum[blockIdx.x] = sh[255];  // block total
}

__global__ void k_scan_b(int* __restrict__ bsum){
  __shared__ int sh[256];
  int v = (threadIdx.x < NB_SCAN) ? bsum[threadIdx.x] : 0;
  sh[threadIdx.x] = v;
  __syncthreads();
  for (int off=1; off<256; off<<=1){
    int t = (threadIdx.x >= off) ? sh[threadIdx.x-off] : 0;
    __syncthreads();
    sh[threadIdx.x] += t;
    __syncthreads();
  }
  if (threadIdx.x < NB_SCAN) bsum[threadIdx.x] = sh[threadIdx.x] - v;  // exclusive
}

__global__ void k_scan_c(int* __restrict__ rs, const int* __restrict__ bsum,
                         int* __restrict__ cursor){
  int i = blockIdx.x*256 + threadIdx.x;
  if (i >= N_NODESC) return;
  int v = rs[i] + bsum[blockIdx.x];
  rs[i] = v;
  cursor[i] = v;
}

__global__ void k_fill(const int* __restrict__ ei, int* __restrict__ cursor,
                       int* __restrict__ csrc){
  int e = blockIdx.x*blockDim.x + threadIdx.x;
  if (e >= E_TOT) return;
  int s, d; edge_sd(ei, e, s, d);
  int pos = atomicAdd(&cursor[d], 1);
  csrc[pos] = s;
}

// ---------------- layer 1 GEMM: xl1 = x@W1l, xr1 = x@W1r ----------------
#define G1_NPB 8
__global__ void k_gemm1(const float* __restrict__ x, const float* __restrict__ Wl,
                        const float* __restrict__ Wr, float* __restrict__ xl,
                        float* __restrict__ xr){
  __shared__ float xs[G1_NPB][IN_CH];
  int t = threadIdx.x;               // 256
  int node0 = blockIdx.x * G1_NPB;
  for (int i = t; i < G1_NPB*IN_CH; i += 256){
    int r = i >> 7, c = i & 127;
    xs[r][c] = x[(size_t)(node0 + r)*IN_CH + c];
  }
  __syncthreads();
  int col = t & 127;
  const float* __restrict__ W = (t < 128) ? Wl : Wr;
  float* __restrict__ O = (t < 128) ? xl : xr;
  float acc[G1_NPB];
  #pragma unroll
  for (int i=0;i<G1_NPB;i++) acc[i]=0.f;
  for (int k=0;k<IN_CH;k++){
    float w = W[k*HC + col];
    #pragma unroll
    for (int i=0;i<G1_NPB;i++) acc[i] += xs[i][k] * w;
  }
  #pragma unroll
  for (int i=0;i<G1_NPB;i++) O[(size_t)(node0+i)*HC + col] = acc[i];
}

// ---------------- layer 2 GEMM: xl2 = h@W2l, xr2 = h@W2r ----------------
#define G2_NPB 8
__global__ void k_gemm2(const float* __restrict__ h, const float* __restrict__ Wl,
                        const float* __restrict__ Wr, float* __restrict__ xl,
                        float* __restrict__ xr){
  __shared__ float hs[G2_NPB][HC];
  int t = threadIdx.x;               // 128
  int node0 = blockIdx.x * G2_NPB;
  for (int i = t; i < G2_NPB*HC; i += 128){
    int r = i >> 7, c = i & 127;
    hs[r][c] = h[(size_t)(node0 + r)*HC + c];
  }
  __syncthreads();
  int col = t & 63;
  const float* __restrict__ W = (t < 64) ? Wl : Wr;
  float* __restrict__ O = (t < 64) ? xl : xr;
  float acc[G2_NPB];
  #pragma unroll
  for (int i=0;i<G2_NPB;i++) acc[i]=0.f;
  for (int k=0;k<HC;k++){
    float w = W[k*OUT_CH + col];
    #pragma unroll
    for (int i=0;i<G2_NPB;i++) acc[i] += hs[i][k] * w;
  }
  #pragma unroll
  for (int i=0;i<G2_NPB;i++) O[(size_t)(node0+i)*OUT_CH + col] = acc[i];
}

// ---------------- layer 1 fused: per-dst online-softmax aggregate + bias + ELU ----------------
// wave per destination. lane l holds channels {2l, 2l+1}; head = l>>4 (both
// channels of a lane are in the same head since HID=32).
__global__ void k_fused1(const int* __restrict__ rs, const int* __restrict__ deg,
                         const int* __restrict__ csrc,
                         const float* __restrict__ xl, const float* __restrict__ xr,
                         const float* __restrict__ att, const float* __restrict__ b1,
                         float* __restrict__ h){
  int wave = threadIdx.x >> 6;
  int lane = threadIdx.x & 63;
  int d = blockIdx.x*4 + wave;
  if (d >= N_NODESC) return;

  const float2* __restrict__ xr_row = (const float2*)(xr + (size_t)d*HC);
  float2 xrv = xr_row[lane];
  float2 atv = ((const float2*)att)[lane];
  float2 bv  = ((const float2*)b1)[lane];

  int start = rs[d];
  int degd  = deg[d];

  float m = -INFINITY, lden = 0.f;
  float2 acc = {0.f, 0.f};

  int s = csrc[start];
  for (int i = 0; i < degd; i++){
    int s_next = (i+1 < degd) ? csrc[start+i+1] : 0;
    float2 xv = ((const float2*)(xl + (size_t)s*HC))[lane];
    float vx = xv.x + xrv.x; vx = (vx > 0.f) ? vx : NEG_SLOPE*vx;
    float vy = xv.y + xrv.y; vy = (vy > 0.f) ? vy : NEG_SLOPE*vy;
    float sc = vx*atv.x + vy*atv.y;
    // reduce within 16-lane head group
    sc += __shfl_xor(sc, 1);
    sc += __shfl_xor(sc, 2);
    sc += __shfl_xor(sc, 4);
    sc += __shfl_xor(sc, 8);
    // online softmax update
    float m_new = fmaxf(m, sc);
    float factor = __expf(m - m_new);
    float p = __expf(sc - m_new);
    m = m_new;
    lden = lden*factor + p;
    acc.x = acc.x*factor + p*xv.x;
    acc.y = acc.y*factor + p*xv.y;
    s = s_next;
  }
  float inv = 1.f / (lden + 1e-16f);
  float ox = acc.x*inv + bv.x;
  float oy = acc.y*inv + bv.y;
  ox = (ox > 0.f) ? ox : (__expf(ox) - 1.f);
  oy = (oy > 0.f) ? oy : (__expf(oy) - 1.f);
  float2 o = {ox, oy};
  ((float2*)(h + (size_t)d*HC))[lane] = o;
}

// ---------------- layer 2 fused: per-dst online-softmax aggregate + bias ----------------
// wave per destination, lane l holds channel l (OUT_CH=64), heads=1.
__global__ void k_fused2(const int* __restrict__ rs, const int* __restrict__ deg,
                         const int* __restrict__ csrc,
                         const float* __restrict__ xl, const float* __restrict__ xr,
                         const float* __restrict__ att, const float* __restrict__ b2,
                         float* __restrict__ out){
  int wave = threadIdx.x >> 6;
  int lane = threadIdx.x & 63;
  int d = blockIdx.x*4 + wave;
  if (d >= N_NODESC) return;

  float xrv = xr[(size_t)d*OUT_CH + lane];
  float atv = att[lane];
  float bv  = b2[lane];

  int start = rs[d];
  int degd  = deg[d];

  float m = -INFINITY, lden = 0.f, acc = 0.f;

  int s = csrc[start];
  for (int i = 0; i < degd; i++){
    int s_next = (i+1 < degd) ? csrc[start+i+1] : 0;
    float xv = xl[(size_t)s*OUT_CH + lane];
    float v = xv + xrv; v = (v > 0.f) ? v : NEG_SLOPE*v;
    float sc = v * atv;
    sc += __shfl_xor(sc, 1);
    sc += __shfl_xor(sc, 2);
    sc += __shfl_xor(sc, 4);
    sc += __shfl_xor(sc, 8);
    sc += __shfl_xor(sc, 16);
    sc += __shfl_xor(sc, 32);
    float m_new = fmaxf(m, sc);
    float factor = __expf(m - m_new);
    float p = __expf(sc - m_new);
    m = m_new;
    lden = lden*factor + p;
    acc  = acc*factor + p*xv;
    s = s_next;
  }
  out[(size_t)d*OUT_CH + lane] = acc / (lden + 1e-16f) + bv;
}

extern "C" void kernel_launch(void* const* d_in, const int* in_sizes, int n_in,
                              void* d_out, int out_size, void* d_ws, size_t ws_size,
                              hipStream_t stream) {
  const float* x    = (const float*)d_in[0];
  const int*   ei   = (const int*)d_in[1];
  const float* W1l  = (const float*)d_in[2];
  const float* W1r  = (const float*)d_in[3];
  const float* att1 = (const float*)d_in[4];
  const float* b1   = (const float*)d_in[5];
  const float* W2l  = (const float*)d_in[6];
  const float* W2r  = (const float*)d_in[7];
  const float* att2 = (const float*)d_in[8];
  const float* b2   = (const float*)d_in[9];
  float* out = (float*)d_out;

  // workspace layout
  float* ws = (float*)d_ws;
  size_t off = 0;
  float* xl1 = ws + off; off += (size_t)N_NODESC*HC;
  float* xr1 = ws + off; off += (size_t)N_NODESC*HC;
  float* h   = ws + off; off += (size_t)N_NODESC*HC;
  float* xl2 = ws + off; off += (size_t)N_NODESC*OUT_CH;
  float* xr2 = ws + off; off += (size_t)N_NODESC*OUT_CH;
  int* deg    = (int*)(ws + off); off += N_NODESC;
  int* rs     = (int*)(ws + off); off += N_NODESC;
  int* cursor = (int*)(ws + off); off += N_NODESC;
  int* bsum   = (int*)(ws + off); off += 256;
  int* csrc   = (int*)(ws + off); off += E_TOT;

  // ---- CSR build (graph identical for both layers) ----
  k_zero_deg<<<(N_NODESC+255)/256, 256, 0, stream>>>(deg);
  k_hist<<<(E_TOT+255)/256, 256, 0, stream>>>(ei, deg);
  k_scan_a<<<NB_SCAN, 256, 0, stream>>>(deg, rs, bsum);
  k_scan_b<<<1, 256, 0, stream>>>(bsum);
  k_scan_c<<<NB_SCAN, 256, 0, stream>>>(rs, bsum, cursor);
  k_fill<<<(E_TOT+255)/256, 256, 0, stream>>>(ei, cursor, csrc);

  // ---- layer 1 ----
  k_gemm1<<<N_NODESC/G1_NPB, 256, 0, stream>>>(x, W1l, W1r, xl1, xr1);
  k_fused1<<<(N_NODESC+3)/4, 256, 0, stream>>>(rs, deg, csrc, xl1, xr1, att1, b1, h);

  // ---- layer 2 ----
  k_gemm2<<<N_NODESC/G2_NPB, 128, 0, stream>>>(h, W2l, W2r, xl2, xr2);
  k_fused2<<<(N_NODESC+3)/4, 256, 0, stream>>>(rs, deg, csrc, xl2, xr2, att2, b2, out);
}

// Round 4
// 340.760 us; speedup vs baseline: 2.4518x; 1.1180x over previous
//
#include <hip/hip_runtime.h>
#include <hip/hip_bf16.h>
#include <math.h>

#define N_NODESC 50000
#define N_EDGESC 500000
#define E_TOT    (N_EDGESC + N_NODESC)   // 550000 (self-loops appended)
#define IN_CH 128
#define HID 32
#define HEADS 4
#define HC (HEADS*HID)    // 128
#define OUT_CH 64
#define NEG_SLOPE 0.2f
#define NB_SCAN 196        // ceil(50000/256)
#define N_STRIPS (N_NODESC/16)   // 3125 exact

typedef unsigned short u16;
typedef __attribute__((ext_vector_type(8))) short short8;   // 8 bf16 (4 VGPRs)
typedef __attribute__((ext_vector_type(4))) float floatx4;  // 4 fp32 acc

// manual bf16 round-to-nearest-even (avoids __hip_bfloat16 ABI uncertainty)
__device__ __forceinline__ u16 f2bf(float f){
  unsigned u = __float_as_uint(f);
  return (u16)((u + 0x7FFFu + ((u >> 16) & 1u)) >> 16);
}
__device__ __forceinline__ float bf2f(u16 b){ return __uint_as_float(((unsigned)b) << 16); }

__device__ __forceinline__ void edge_sd(const int* __restrict__ ei, int e, int& s, int& d){
  if (e < N_EDGESC){ s = ei[e]; d = ei[N_EDGESC + e]; }
  else { s = e - N_EDGESC; d = s; }
}

// ---------------- CSR build ----------------
__global__ void k_zero_deg(int* __restrict__ deg){
  int i = blockIdx.x*blockDim.x + threadIdx.x;
  if (i < N_NODESC) deg[i] = 0;
}

__global__ void k_hist(const int* __restrict__ ei, int* __restrict__ deg){
  int e = blockIdx.x*blockDim.x + threadIdx.x;
  if (e >= E_TOT) return;
  int s, d; edge_sd(ei, e, s, d);
  atomicAdd(&deg[d], 1);
}

__global__ void k_scan_a(const int* __restrict__ deg, int* __restrict__ rs,
                         int* __restrict__ bsum){
  __shared__ int sh[256];
  int i = blockIdx.x*256 + threadIdx.x;
  int v = (i < N_NODESC) ? deg[i] : 0;
  sh[threadIdx.x] = v;
  __syncthreads();
  for (int off=1; off<256; off<<=1){
    int t = (threadIdx.x >= off) ? sh[threadIdx.x-off] : 0;
    __syncthreads();
    sh[threadIdx.x] += t;
    __syncthreads();
  }
  if (i < N_NODESC) rs[i] = sh[threadIdx.x] - v;       // exclusive within block
  if (threadIdx.x == 255) bsum[blockIdx.x] = sh[255];  // block total
}

__global__ void k_scan_b(int* __restrict__ bsum){
  __shared__ int sh[256];
  int v = (threadIdx.x < NB_SCAN) ? bsum[threadIdx.x] : 0;
  sh[threadIdx.x] = v;
  __syncthreads();
  for (int off=1; off<256; off<<=1){
    int t = (threadIdx.x >= off) ? sh[threadIdx.x-off] : 0;
    __syncthreads();
    sh[threadIdx.x] += t;
    __syncthreads();
  }
  if (threadIdx.x < NB_SCAN) bsum[threadIdx.x] = sh[threadIdx.x] - v;  // exclusive
}

__global__ void k_scan_c(int* __restrict__ rs, const int* __restrict__ bsum,
                         int* __restrict__ cursor){
  int i = blockIdx.x*256 + threadIdx.x;
  if (i >= N_NODESC) return;
  int v = rs[i] + bsum[blockIdx.x];
  rs[i] = v;
  cursor[i] = v;
}

__global__ void k_fill(const int* __restrict__ ei, int* __restrict__ cursor,
                       int* __restrict__ csrc){
  int e = blockIdx.x*blockDim.x + threadIdx.x;
  if (e >= E_TOT) return;
  int s, d; edge_sd(ei, e, s, d);
  int pos = atomicAdd(&cursor[d], 1);
  csrc[pos] = s;
}

// ---------------- split x into bf16 hi/lo ----------------
__global__ void k_split(const float* __restrict__ X, u16* __restrict__ hi,
                        u16* __restrict__ lo, int total4){
  int i = blockIdx.x*blockDim.x + threadIdx.x;
  if (i >= total4) return;
  float4 v = ((const float4*)X)[i];
  ushort4 h, l;
  h.x = f2bf(v.x); l.x = f2bf(v.x - bf2f(h.x));
  h.y = f2bf(v.y); l.y = f2bf(v.y - bf2f(h.y));
  h.z = f2bf(v.z); l.z = f2bf(v.z - bf2f(h.z));
  h.w = f2bf(v.w); l.w = f2bf(v.w - bf2f(h.w));
  ((ushort4*)hi)[i] = h;
  ((ushort4*)lo)[i] = l;
}

// ---------------- weight prep: pack W [K=128 x N] into B-fragment layout ----------------
// packed idx = (((c*4 + t)*64) + lane)*8 + j
// value      = W[(t*32 + (lane>>4)*8 + j)*N + c*16 + (lane&15)]   (hi/lo split)
__global__ void k_prep_w(const float* __restrict__ W, int N,
                         u16* __restrict__ Thi, u16* __restrict__ Tlo){
  int tid = blockIdx.x*blockDim.x + threadIdx.x;   // one per (c,t,lane)
  int total = (N/16)*4*64;
  if (tid >= total) return;
  int lane = tid & 63;
  int t = (tid >> 6) & 3;
  int c = tid >> 8;
  int k0 = t*32 + (lane>>4)*8;
  int n  = c*16 + (lane&15);
  u16 hv[8], lv[8];
  #pragma unroll
  for (int j=0;j<8;j++){
    float w = W[(size_t)(k0+j)*N + n];
    u16 h = f2bf(w);
    hv[j] = h;
    lv[j] = f2bf(w - bf2f(h));
  }
  #pragma unroll
  for (int j=0;j<8;j++){ Thi[(size_t)tid*8 + j] = hv[j]; Tlo[(size_t)tid*8 + j] = lv[j]; }
}

// ---------------- split-bf16 MFMA GEMM ----------------
// A: [50000 x 128] bf16 hi/lo row-major. B: packed frag layout (see k_prep_w).
// Computes Ol = A@Wl, Or = A@Wr, each [50000 x NCT*16] fp32.
// One wave per 16-row strip; K=128 (4 k-tiles); 3 MFMAs (hi*hi + lo*hi + hi*lo).
template<int NCT>
__global__ void k_mfma_gemm(const u16* __restrict__ Ahi, const u16* __restrict__ Alo,
                            const u16* __restrict__ BlThi, const u16* __restrict__ BlTlo,
                            const u16* __restrict__ BrThi, const u16* __restrict__ BrTlo,
                            float* __restrict__ Ol, float* __restrict__ Or){
  int wave = threadIdx.x >> 6, lane = threadIdx.x & 63;
  int strip = blockIdx.x*4 + wave;
  if (strip >= N_STRIPS) return;
  int row0 = strip*16;
  int m = lane & 15, quad = lane >> 4;

  short8 ahi[4], alo[4];
  const u16* ab1 = Ahi + (size_t)(row0 + m)*128 + quad*8;
  const u16* ab2 = Alo + (size_t)(row0 + m)*128 + quad*8;
  #pragma unroll
  for (int t=0;t<4;t++){
    ahi[t] = *(const short8*)(ab1 + t*32);
    alo[t] = *(const short8*)(ab2 + t*32);
  }

  floatx4 acc[2*NCT];
  #pragma unroll
  for (int i=0;i<2*NCT;i++) acc[i] = (floatx4){0.f,0.f,0.f,0.f};

  #pragma unroll
  for (int t=0;t<4;t++){
    #pragma unroll
    for (int ct=0; ct<2*NCT; ct++){
      const u16* Bh = (ct < NCT) ? BlThi : BrThi;
      const u16* Bw = (ct < NCT) ? BlTlo : BrTlo;
      int c = (ct < NCT) ? ct : ct - NCT;
      size_t bo = ((size_t)((c*4 + t)*64) + lane)*8;
      short8 bh = *(const short8*)(Bh + bo);
      short8 bl = *(const short8*)(Bw + bo);
      acc[ct] = __builtin_amdgcn_mfma_f32_16x16x32_bf16(ahi[t], bh, acc[ct], 0,0,0);
      acc[ct] = __builtin_amdgcn_mfma_f32_16x16x32_bf16(alo[t], bh, acc[ct], 0,0,0);
      acc[ct] = __builtin_amdgcn_mfma_f32_16x16x32_bf16(ahi[t], bl, acc[ct], 0,0,0);
    }
  }

  const int NLD = NCT*16;
  #pragma unroll
  for (int ct=0; ct<2*NCT; ct++){
    float* O = (ct < NCT) ? Ol : Or;
    int c = (ct < NCT) ? ct : ct - NCT;
    #pragma unroll
    for (int r=0;r<4;r++)
      O[(size_t)(row0 + quad*4 + r)*NLD + c*16 + m] = acc[ct][r];
  }
}

// ---------------- layer 1 fused: per-dst online-softmax aggregate + bias + ELU ----------------
// wave per destination. lane l holds channels {2l, 2l+1}; head = l>>4.
// Emits h split into bf16 hi/lo (A-operand for layer-2 MFMA GEMM).
__global__ void k_fused1(const int* __restrict__ rs, const int* __restrict__ deg,
                         const int* __restrict__ csrc,
                         const float* __restrict__ xl, const float* __restrict__ xr,
                         const float* __restrict__ att, const float* __restrict__ b1,
                         u16* __restrict__ Hhi, u16* __restrict__ Hlo){
  int wave = threadIdx.x >> 6;
  int lane = threadIdx.x & 63;
  int d = blockIdx.x*4 + wave;
  if (d >= N_NODESC) return;

  float2 xrv = ((const float2*)(xr + (size_t)d*HC))[lane];
  float2 atv = ((const float2*)att)[lane];
  float2 bv  = ((const float2*)b1)[lane];

  int start = rs[d];
  int degd  = deg[d];

  float m = -INFINITY, lden = 0.f;
  float2 acc = {0.f, 0.f};

  int s = csrc[start];
  for (int i = 0; i < degd; i++){
    int s_next = (i+1 < degd) ? csrc[start+i+1] : 0;
    float2 xv = ((const float2*)(xl + (size_t)s*HC))[lane];
    float vx = xv.x + xrv.x; vx = (vx > 0.f) ? vx : NEG_SLOPE*vx;
    float vy = xv.y + xrv.y; vy = (vy > 0.f) ? vy : NEG_SLOPE*vy;
    float sc = vx*atv.x + vy*atv.y;
    sc += __shfl_xor(sc, 1);
    sc += __shfl_xor(sc, 2);
    sc += __shfl_xor(sc, 4);
    sc += __shfl_xor(sc, 8);
    float m_new = fmaxf(m, sc);
    float factor = __expf(m - m_new);
    float p = __expf(sc - m_new);
    m = m_new;
    lden = lden*factor + p;
    acc.x = acc.x*factor + p*xv.x;
    acc.y = acc.y*factor + p*xv.y;
    s = s_next;
  }
  float inv = 1.f / (lden + 1e-16f);
  float ox = acc.x*inv + bv.x;
  float oy = acc.y*inv + bv.y;
  ox = (ox > 0.f) ? ox : (__expf(ox) - 1.f);
  oy = (oy > 0.f) ? oy : (__expf(oy) - 1.f);

  u16 hx = f2bf(ox), hy = f2bf(oy);
  ushort2 hh; hh.x = hx; hh.y = hy;
  ushort2 hl; hl.x = f2bf(ox - bf2f(hx)); hl.y = f2bf(oy - bf2f(hy));
  ((ushort2*)(Hhi + (size_t)d*HC))[lane] = hh;
  ((ushort2*)(Hlo + (size_t)d*HC))[lane] = hl;
}

// ---------------- layer 2 fused: per-dst online-softmax aggregate + bias ----------------
__global__ void k_fused2(const int* __restrict__ rs, const int* __restrict__ deg,
                         const int* __restrict__ csrc,
                         const float* __restrict__ xl, const float* __restrict__ xr,
                         const float* __restrict__ att, const float* __restrict__ b2,
                         float* __restrict__ out){
  int wave = threadIdx.x >> 6;
  int lane = threadIdx.x & 63;
  int d = blockIdx.x*4 + wave;
  if (d >= N_NODESC) return;

  float xrv = xr[(size_t)d*OUT_CH + lane];
  float atv = att[lane];
  float bv  = b2[lane];

  int start = rs[d];
  int degd  = deg[d];

  float m = -INFINITY, lden = 0.f, acc = 0.f;

  int s = csrc[start];
  for (int i = 0; i < degd; i++){
    int s_next = (i+1 < degd) ? csrc[start+i+1] : 0;
    float xv = xl[(size_t)s*OUT_CH + lane];
    float v = xv + xrv; v = (v > 0.f) ? v : NEG_SLOPE*v;
    float sc = v * atv;
    sc += __shfl_xor(sc, 1);
    sc += __shfl_xor(sc, 2);
    sc += __shfl_xor(sc, 4);
    sc += __shfl_xor(sc, 8);
    sc += __shfl_xor(sc, 16);
    sc += __shfl_xor(sc, 32);
    float m_new = fmaxf(m, sc);
    float factor = __expf(m - m_new);
    float p = __expf(sc - m_new);
    m = m_new;
    lden = lden*factor + p;
    acc  = acc*factor + p*xv;
    s = s_next;
  }
  out[(size_t)d*OUT_CH + lane] = acc / (lden + 1e-16f) + bv;
}

extern "C" void kernel_launch(void* const* d_in, const int* in_sizes, int n_in,
                              void* d_out, int out_size, void* d_ws, size_t ws_size,
                              hipStream_t stream) {
  const float* x    = (const float*)d_in[0];
  const int*   ei   = (const int*)d_in[1];
  const float* W1l  = (const float*)d_in[2];
  const float* W1r  = (const float*)d_in[3];
  const float* att1 = (const float*)d_in[4];
  const float* b1   = (const float*)d_in[5];
  const float* W2l  = (const float*)d_in[6];
  const float* W2r  = (const float*)d_in[7];
  const float* att2 = (const float*)d_in[8];
  const float* b2   = (const float*)d_in[9];
  float* out = (float*)d_out;

  // workspace layout (units of float; all offsets multiples of 4 -> 16B aligned)
  float* ws = (float*)d_ws;
  size_t off = 0;
  float* xl1 = ws + off; off += (size_t)N_NODESC*HC;        // 6.4M
  float* xr1 = ws + off; off += (size_t)N_NODESC*HC;
  float* xl2 = ws + off; off += (size_t)N_NODESC*OUT_CH;    // 3.2M
  float* xr2 = ws + off; off += (size_t)N_NODESC*OUT_CH;
  u16* xhi = (u16*)(ws + off); off += (size_t)N_NODESC*HC/2;  // bf16 [N x 128]
  u16* xlo = (u16*)(ws + off); off += (size_t)N_NODESC*HC/2;
  u16* hhi = (u16*)(ws + off); off += (size_t)N_NODESC*HC/2;
  u16* hlo = (u16*)(ws + off); off += (size_t)N_NODESC*HC/2;
  u16* w1lhi = (u16*)(ws + off); off += IN_CH*HC/2;   // 16384 u16 = 8192 floats? (128*128/2=8192)
  u16* w1llo = (u16*)(ws + off); off += IN_CH*HC/2;
  u16* w1rhi = (u16*)(ws + off); off += IN_CH*HC/2;
  u16* w1rlo = (u16*)(ws + off); off += IN_CH*HC/2;
  u16* w2lhi = (u16*)(ws + off); off += HC*OUT_CH/2;
  u16* w2llo = (u16*)(ws + off); off += HC*OUT_CH/2;
  u16* w2rhi = (u16*)(ws + off); off += HC*OUT_CH/2;
  u16* w2rlo = (u16*)(ws + off); off += HC*OUT_CH/2;
  int* deg    = (int*)(ws + off); off += N_NODESC;
  int* rs     = (int*)(ws + off); off += N_NODESC;
  int* cursor = (int*)(ws + off); off += N_NODESC;
  int* bsum   = (int*)(ws + off); off += 256;
  int* csrc   = (int*)(ws + off); off += E_TOT;

  // ---- CSR build (graph identical for both layers) ----
  k_zero_deg<<<(N_NODESC+255)/256, 256, 0, stream>>>(deg);
  k_hist<<<(E_TOT+255)/256, 256, 0, stream>>>(ei, deg);
  k_scan_a<<<NB_SCAN, 256, 0, stream>>>(deg, rs, bsum);
  k_scan_b<<<1, 256, 0, stream>>>(bsum);
  k_scan_c<<<NB_SCAN, 256, 0, stream>>>(rs, bsum, cursor);
  k_fill<<<(E_TOT+255)/256, 256, 0, stream>>>(ei, cursor, csrc);

  // ---- input split + weight packing ----
  k_split<<<((N_NODESC*HC/4)+255)/256, 256, 0, stream>>>(x, xhi, xlo, N_NODESC*HC/4);
  k_prep_w<<<8, 256, 0, stream>>>(W1l, HC,     w1lhi, w1llo);
  k_prep_w<<<8, 256, 0, stream>>>(W1r, HC,     w1rhi, w1rlo);
  k_prep_w<<<4, 256, 0, stream>>>(W2l, OUT_CH, w2lhi, w2llo);
  k_prep_w<<<4, 256, 0, stream>>>(W2r, OUT_CH, w2rhi, w2rlo);

  // ---- layer 1 ----
  k_mfma_gemm<8><<<(N_STRIPS+3)/4, 256, 0, stream>>>(xhi, xlo, w1lhi, w1llo,
                                                     w1rhi, w1rlo, xl1, xr1);
  k_fused1<<<(N_NODESC+3)/4, 256, 0, stream>>>(rs, deg, csrc, xl1, xr1, att1, b1, hhi, hlo);

  // ---- layer 2 ----
  k_mfma_gemm<4><<<(N_STRIPS+3)/4, 256, 0, stream>>>(hhi, hlo, w2lhi, w2llo,
                                                     w2rhi, w2rlo, xl2, xr2);
  k_fused2<<<(N_NODESC+3)/4, 256, 0, stream>>>(rs, deg, csrc, xl2, xr2, att2, b2, out);
}

// Round 5
// 295.219 us; speedup vs baseline: 2.8300x; 1.1543x over previous
//
#include <hip/hip_runtime.h>
#include <hip/hip_bf16.h>
#include <math.h>

#define N_NODESC 50000
#define N_EDGESC 500000
#define E_TOT    (N_EDGESC + N_NODESC)   // 550000 (self-loops appended)
#define IN_CH 128
#define HID 32
#define HEADS 4
#define HC (HEADS*HID)    // 128
#define OUT_CH 64
#define NEG_SLOPE 0.2f
#define NB_SCAN 196        // ceil(50000/256)
#define N_STRIPS (N_NODESC/16)   // 3125 exact

typedef unsigned short u16;
typedef __attribute__((ext_vector_type(8))) short short8;   // 8 bf16 (4 VGPRs)
typedef __attribute__((ext_vector_type(4))) float floatx4;  // 4 fp32 acc

// manual bf16 round-to-nearest-even
__device__ __forceinline__ u16 f2bf(float f){
  unsigned u = __float_as_uint(f);
  return (u16)((u + 0x7FFFu + ((u >> 16) & 1u)) >> 16);
}
__device__ __forceinline__ float bf2f(u16 b){ return __uint_as_float(((unsigned)b) << 16); }
__device__ __forceinline__ float bflo(unsigned q){ return __uint_as_float(q << 16); }
__device__ __forceinline__ float bfhi(unsigned q){ return __uint_as_float(q & 0xFFFF0000u); }
__device__ __forceinline__ float lrelu(float v){ return (v > 0.f) ? v : NEG_SLOPE*v; }

__device__ __forceinline__ void edge_sd(const int* __restrict__ ei, int e, int& s, int& d){
  if (e < N_EDGESC){ s = ei[e]; d = ei[N_EDGESC + e]; }
  else { s = e - N_EDGESC; d = s; }
}

// ---------------- CSR build ----------------
__global__ void k_zero_deg(int* __restrict__ deg){
  int i = blockIdx.x*blockDim.x + threadIdx.x;
  if (i < N_NODESC) deg[i] = 0;
}

__global__ void k_hist(const int* __restrict__ ei, int* __restrict__ deg){
  int e = blockIdx.x*blockDim.x + threadIdx.x;
  if (e >= E_TOT) return;
  int s, d; edge_sd(ei, e, s, d);
  atomicAdd(&deg[d], 1);
}

__global__ void k_scan_a(const int* __restrict__ deg, int* __restrict__ rs,
                         int* __restrict__ bsum){
  __shared__ int sh[256];
  int i = blockIdx.x*256 + threadIdx.x;
  int v = (i < N_NODESC) ? deg[i] : 0;
  sh[threadIdx.x] = v;
  __syncthreads();
  for (int off=1; off<256; off<<=1){
    int t = (threadIdx.x >= off) ? sh[threadIdx.x-off] : 0;
    __syncthreads();
    sh[threadIdx.x] += t;
    __syncthreads();
  }
  if (i < N_NODESC) rs[i] = sh[threadIdx.x] - v;
  if (threadIdx.x == 255) bsum[blockIdx.x] = sh[255];
}

__global__ void k_scan_b(int* __restrict__ bsum){
  __shared__ int sh[256];
  int v = (threadIdx.x < NB_SCAN) ? bsum[threadIdx.x] : 0;
  sh[threadIdx.x] = v;
  __syncthreads();
  for (int off=1; off<256; off<<=1){
    int t = (threadIdx.x >= off) ? sh[threadIdx.x-off] : 0;
    __syncthreads();
    sh[threadIdx.x] += t;
    __syncthreads();
  }
  if (threadIdx.x < NB_SCAN) bsum[threadIdx.x] = sh[threadIdx.x] - v;
}

__global__ void k_scan_c(int* __restrict__ rs, const int* __restrict__ bsum,
                         int* __restrict__ cursor){
  int i = blockIdx.x*256 + threadIdx.x;
  if (i >= N_NODESC) return;
  int v = rs[i] + bsum[blockIdx.x];
  rs[i] = v;
  cursor[i] = v;
}

__global__ void k_fill(const int* __restrict__ ei, int* __restrict__ cursor,
                       int* __restrict__ csrc){
  int e = blockIdx.x*blockDim.x + threadIdx.x;
  if (e >= E_TOT) return;
  int s, d; edge_sd(ei, e, s, d);
  int pos = atomicAdd(&cursor[d], 1);
  csrc[pos] = s;
}

// ---------------- split x into bf16 hi/lo (A operand for gemm1) ----------------
__global__ void k_split(const float* __restrict__ X, u16* __restrict__ hi,
                        u16* __restrict__ lo, int total4){
  int i = blockIdx.x*blockDim.x + threadIdx.x;
  if (i >= total4) return;
  float4 v = ((const float4*)X)[i];
  ushort4 h, l;
  h.x = f2bf(v.x); l.x = f2bf(v.x - bf2f(h.x));
  h.y = f2bf(v.y); l.y = f2bf(v.y - bf2f(h.y));
  h.z = f2bf(v.z); l.z = f2bf(v.z - bf2f(h.z));
  h.w = f2bf(v.w); l.w = f2bf(v.w - bf2f(h.w));
  ((ushort4*)hi)[i] = h;
  ((ushort4*)lo)[i] = l;
}

// ---------------- weight prep: all 4 weights in one launch ----------------
// packed idx = (((c*4 + t)*64) + lane)*8 + j
// value      = W[(t*32 + (lane>>4)*8 + j)*N + c*16 + (lane&15)]   (hi/lo split)
__global__ void k_prep_all(const float* __restrict__ W1l, const float* __restrict__ W1r,
                           const float* __restrict__ W2l, const float* __restrict__ W2r,
                           u16* __restrict__ w1lhi, u16* __restrict__ w1llo,
                           u16* __restrict__ w1rhi, u16* __restrict__ w1rlo,
                           u16* __restrict__ w2lhi, u16* __restrict__ w2llo,
                           u16* __restrict__ w2rhi, u16* __restrict__ w2rlo){
  int b = blockIdx.x;
  const float* W; u16 *Th, *Tl; int N, base;
  if (b < 8)      { W=W1l; Th=w1lhi; Tl=w1llo; N=HC;     base=b;    }
  else if (b < 16){ W=W1r; Th=w1rhi; Tl=w1rlo; N=HC;     base=b-8;  }
  else if (b < 20){ W=W2l; Th=w2lhi; Tl=w2llo; N=OUT_CH; base=b-16; }
  else            { W=W2r; Th=w2rhi; Tl=w2rlo; N=OUT_CH; base=b-20; }
  int tid = base*256 + threadIdx.x;
  int lane = tid & 63;
  int t = (tid >> 6) & 3;
  int c = tid >> 8;
  int k0 = t*32 + (lane>>4)*8;
  int n  = c*16 + (lane&15);
  #pragma unroll
  for (int j=0;j<8;j++){
    float w = W[(size_t)(k0+j)*N + n];
    u16 h = f2bf(w);
    Th[(size_t)tid*8 + j] = h;
    Tl[(size_t)tid*8 + j] = f2bf(w - bf2f(h));
  }
}

// ---------------- split-bf16 MFMA GEMM ----------------
// Ol written as bf16 (gather table for fused kernels), Or as fp32.
template<int NCT>
__global__ void k_mfma_gemm(const u16* __restrict__ Ahi, const u16* __restrict__ Alo,
                            const u16* __restrict__ BlThi, const u16* __restrict__ BlTlo,
                            const u16* __restrict__ BrThi, const u16* __restrict__ BrTlo,
                            u16* __restrict__ Olb, float* __restrict__ Or){
  int wave = threadIdx.x >> 6, lane = threadIdx.x & 63;
  int strip = blockIdx.x*4 + wave;
  if (strip >= N_STRIPS) return;
  int row0 = strip*16;
  int m = lane & 15, quad = lane >> 4;

  short8 ahi[4], alo[4];
  const u16* ab1 = Ahi + (size_t)(row0 + m)*128 + quad*8;
  const u16* ab2 = Alo + (size_t)(row0 + m)*128 + quad*8;
  #pragma unroll
  for (int t=0;t<4;t++){
    ahi[t] = *(const short8*)(ab1 + t*32);
    alo[t] = *(const short8*)(ab2 + t*32);
  }

  floatx4 acc[2*NCT];
  #pragma unroll
  for (int i=0;i<2*NCT;i++) acc[i] = (floatx4){0.f,0.f,0.f,0.f};

  #pragma unroll
  for (int t=0;t<4;t++){
    #pragma unroll
    for (int ct=0; ct<2*NCT; ct++){
      const u16* Bh = (ct < NCT) ? BlThi : BrThi;
      const u16* Bw = (ct < NCT) ? BlTlo : BrTlo;
      int c = (ct < NCT) ? ct : ct - NCT;
      size_t bo = ((size_t)((c*4 + t)*64) + lane)*8;
      short8 bh = *(const short8*)(Bh + bo);
      short8 bl = *(const short8*)(Bw + bo);
      acc[ct] = __builtin_amdgcn_mfma_f32_16x16x32_bf16(ahi[t], bh, acc[ct], 0,0,0);
      acc[ct] = __builtin_amdgcn_mfma_f32_16x16x32_bf16(alo[t], bh, acc[ct], 0,0,0);
      acc[ct] = __builtin_amdgcn_mfma_f32_16x16x32_bf16(ahi[t], bl, acc[ct], 0,0,0);
    }
  }

  const int NLD = NCT*16;
  #pragma unroll
  for (int ct=0; ct<NCT; ct++){
    #pragma unroll
    for (int r=0;r<4;r++)
      Olb[(size_t)(row0 + quad*4 + r)*NLD + ct*16 + m] = f2bf(acc[ct][r]);
  }
  #pragma unroll
  for (int ct=NCT; ct<2*NCT; ct++){
    int c = ct - NCT;
    #pragma unroll
    for (int r=0;r<4;r++)
      Or[(size_t)(row0 + quad*4 + r)*NLD + c*16 + m] = acc[ct][r];
  }
}

// ---------------- layer 1 fused: per-dst softmax aggregate + bias + ELU ----------------
// wave per destination; lane holds channels {2l,2l+1} (same head, HID=32).
// xlb: bf16 gather table [N x 128]. No max-subtraction (|score| ~ O(5), exp safe;
// alpha invariant to per-dst constants) -> iterations independent, 4-way unrolled.
__global__ void k_fused1(const int* __restrict__ rs, const int* __restrict__ deg,
                         const int* __restrict__ csrc, const u16* __restrict__ xlb,
                         const float* __restrict__ xr, const float* __restrict__ att,
                         const float* __restrict__ b1,
                         u16* __restrict__ Hhi, u16* __restrict__ Hlo){
  int wave = threadIdx.x >> 6;
  int lane = threadIdx.x & 63;
  int d = blockIdx.x*4 + wave;
  if (d >= N_NODESC) return;

  float2 xrv = ((const float2*)(xr + (size_t)d*HC))[lane];
  float2 atv = ((const float2*)att)[lane];
  float2 bv  = ((const float2*)b1)[lane];

  int start = rs[d];
  int degd  = deg[d];
  const unsigned* __restrict__ xt = (const unsigned*)xlb;  // [N x 64] uints

  float lden = 0.f;
  float2 acc = {0.f, 0.f};

  int i = 0;
  int s0=0,s1=0,s2=0,s3=0;
  if (degd >= 4){
    s0 = csrc[start+0]; s1 = csrc[start+1]; s2 = csrc[start+2]; s3 = csrc[start+3];
  }
  for (; i + 4 <= degd; ){
    int t0=s0, t1=s1, t2=s2, t3=s3;
    int ni = i + 4;
    if (ni + 4 <= degd){
      s0 = csrc[start+ni+0]; s1 = csrc[start+ni+1];
      s2 = csrc[start+ni+2]; s3 = csrc[start+ni+3];
    }
    unsigned q0 = xt[(size_t)t0*64 + lane];
    unsigned q1 = xt[(size_t)t1*64 + lane];
    unsigned q2 = xt[(size_t)t2*64 + lane];
    unsigned q3 = xt[(size_t)t3*64 + lane];

    float sc0 = lrelu(bflo(q0)+xrv.x)*atv.x + lrelu(bfhi(q0)+xrv.y)*atv.y;
    float sc1 = lrelu(bflo(q1)+xrv.x)*atv.x + lrelu(bfhi(q1)+xrv.y)*atv.y;
    float sc2 = lrelu(bflo(q2)+xrv.x)*atv.x + lrelu(bfhi(q2)+xrv.y)*atv.y;
    float sc3 = lrelu(bflo(q3)+xrv.x)*atv.x + lrelu(bfhi(q3)+xrv.y)*atv.y;
    #pragma unroll
    for (int off=1; off<16; off<<=1){
      sc0 += __shfl_xor(sc0, off);
      sc1 += __shfl_xor(sc1, off);
      sc2 += __shfl_xor(sc2, off);
      sc3 += __shfl_xor(sc3, off);
    }
    float p0 = __expf(sc0), p1 = __expf(sc1), p2 = __expf(sc2), p3 = __expf(sc3);
    lden += (p0+p1) + (p2+p3);
    acc.x += p0*bflo(q0) + p1*bflo(q1) + p2*bflo(q2) + p3*bflo(q3);
    acc.y += p0*bfhi(q0) + p1*bfhi(q1) + p2*bfhi(q2) + p3*bfhi(q3);
    i = ni;
  }
  for (; i < degd; i++){
    int s = csrc[start+i];
    unsigned q = xt[(size_t)s*64 + lane];
    float sc = lrelu(bflo(q)+xrv.x)*atv.x + lrelu(bfhi(q)+xrv.y)*atv.y;
    #pragma unroll
    for (int off=1; off<16; off<<=1) sc += __shfl_xor(sc, off);
    float p = __expf(sc);
    lden += p;
    acc.x += p*bflo(q);
    acc.y += p*bfhi(q);
  }

  float inv = 1.f / (lden + 1e-16f);
  float ox = acc.x*inv + bv.x;
  float oy = acc.y*inv + bv.y;
  ox = (ox > 0.f) ? ox : (__expf(ox) - 1.f);
  oy = (oy > 0.f) ? oy : (__expf(oy) - 1.f);

  u16 hx = f2bf(ox), hy = f2bf(oy);
  ushort2 hh; hh.x = hx; hh.y = hy;
  ushort2 hl; hl.x = f2bf(ox - bf2f(hx)); hl.y = f2bf(oy - bf2f(hy));
  ((ushort2*)(Hhi + (size_t)d*HC))[lane] = hh;
  ((ushort2*)(Hlo + (size_t)d*HC))[lane] = hl;
}

// ---------------- layer 2 fused: per-dst softmax aggregate + bias ----------------
// wave per destination, lane = channel (OUT_CH=64), heads=1. xlb: bf16 [N x 64].
__global__ void k_fused2(const int* __restrict__ rs, const int* __restrict__ deg,
                         const int* __restrict__ csrc, const u16* __restrict__ xlb,
                         const float* __restrict__ xr, const float* __restrict__ att,
                         const float* __restrict__ b2, float* __restrict__ out){
  int wave = threadIdx.x >> 6;
  int lane = threadIdx.x & 63;
  int d = blockIdx.x*4 + wave;
  if (d >= N_NODESC) return;

  float xrv = xr[(size_t)d*OUT_CH + lane];
  float atv = att[lane];
  float bv  = b2[lane];

  int start = rs[d];
  int degd  = deg[d];

  float lden = 0.f, acc = 0.f;

  int i = 0;
  int s0=0,s1=0,s2=0,s3=0;
  if (degd >= 4){
    s0 = csrc[start+0]; s1 = csrc[start+1]; s2 = csrc[start+2]; s3 = csrc[start+3];
  }
  for (; i + 4 <= degd; ){
    int t0=s0, t1=s1, t2=s2, t3=s3;
    int ni = i + 4;
    if (ni + 4 <= degd){
      s0 = csrc[start+ni+0]; s1 = csrc[start+ni+1];
      s2 = csrc[start+ni+2]; s3 = csrc[start+ni+3];
    }
    float x0 = bf2f(xlb[(size_t)t0*OUT_CH + lane]);
    float x1 = bf2f(xlb[(size_t)t1*OUT_CH + lane]);
    float x2 = bf2f(xlb[(size_t)t2*OUT_CH + lane]);
    float x3 = bf2f(xlb[(size_t)t3*OUT_CH + lane]);

    float sc0 = lrelu(x0+xrv)*atv;
    float sc1 = lrelu(x1+xrv)*atv;
    float sc2 = lrelu(x2+xrv)*atv;
    float sc3 = lrelu(x3+xrv)*atv;
    #pragma unroll
    for (int off=1; off<64; off<<=1){
      sc0 += __shfl_xor(sc0, off);
      sc1 += __shfl_xor(sc1, off);
      sc2 += __shfl_xor(sc2, off);
      sc3 += __shfl_xor(sc3, off);
    }
    float p0 = __expf(sc0), p1 = __expf(sc1), p2 = __expf(sc2), p3 = __expf(sc3);
    lden += (p0+p1) + (p2+p3);
    acc += p0*x0 + p1*x1 + p2*x2 + p3*x3;
    i = ni;
  }
  for (; i < degd; i++){
    int s = csrc[start+i];
    float xv = bf2f(xlb[(size_t)s*OUT_CH + lane]);
    float sc = lrelu(xv+xrv)*atv;
    #pragma unroll
    for (int off=1; off<64; off<<=1) sc += __shfl_xor(sc, off);
    float p = __expf(sc);
    lden += p;
    acc  += p*xv;
  }
  out[(size_t)d*OUT_CH + lane] = acc / (lden + 1e-16f) + bv;
}

extern "C" void kernel_launch(void* const* d_in, const int* in_sizes, int n_in,
                              void* d_out, int out_size, void* d_ws, size_t ws_size,
                              hipStream_t stream) {
  const float* x    = (const float*)d_in[0];
  const int*   ei   = (const int*)d_in[1];
  const float* W1l  = (const float*)d_in[2];
  const float* W1r  = (const float*)d_in[3];
  const float* att1 = (const float*)d_in[4];
  const float* b1   = (const float*)d_in[5];
  const float* W2l  = (const float*)d_in[6];
  const float* W2r  = (const float*)d_in[7];
  const float* att2 = (const float*)d_in[8];
  const float* b2   = (const float*)d_in[9];
  float* out = (float*)d_out;

  // workspace layout (units of float; offsets multiples of 4 -> 16B aligned)
  float* ws = (float*)d_ws;
  size_t off = 0;
  float* xr1 = ws + off; off += (size_t)N_NODESC*HC;          // fp32 [N x 128]
  float* xr2 = ws + off; off += (size_t)N_NODESC*OUT_CH;      // fp32 [N x 64]
  u16* xl1b = (u16*)(ws + off); off += (size_t)N_NODESC*HC/2;     // bf16 gather [N x 128]
  u16* xl2b = (u16*)(ws + off); off += (size_t)N_NODESC*OUT_CH/2; // bf16 gather [N x 64]
  u16* xhi = (u16*)(ws + off); off += (size_t)N_NODESC*HC/2;  // A for gemm1
  u16* xlo = (u16*)(ws + off); off += (size_t)N_NODESC*HC/2;
  u16* hhi = (u16*)(ws + off); off += (size_t)N_NODESC*HC/2;  // A for gemm2
  u16* hlo = (u16*)(ws + off); off += (size_t)N_NODESC*HC/2;
  u16* w1lhi = (u16*)(ws + off); off += IN_CH*HC/2;
  u16* w1llo = (u16*)(ws + off); off += IN_CH*HC/2;
  u16* w1rhi = (u16*)(ws + off); off += IN_CH*HC/2;
  u16* w1rlo = (u16*)(ws + off); off += IN_CH*HC/2;
  u16* w2lhi = (u16*)(ws + off); off += HC*OUT_CH/2;
  u16* w2llo = (u16*)(ws + off); off += HC*OUT_CH/2;
  u16* w2rhi = (u16*)(ws + off); off += HC*OUT_CH/2;
  u16* w2rlo = (u16*)(ws + off); off += HC*OUT_CH/2;
  int* deg    = (int*)(ws + off); off += N_NODESC;
  int* rs     = (int*)(ws + off); off += N_NODESC;
  int* cursor = (int*)(ws + off); off += N_NODESC;
  int* bsum   = (int*)(ws + off); off += 256;
  int* csrc   = (int*)(ws + off); off += E_TOT;

  // ---- CSR build (graph identical for both layers) ----
  k_zero_deg<<<(N_NODESC+255)/256, 256, 0, stream>>>(deg);
  k_hist<<<(E_TOT+255)/256, 256, 0, stream>>>(ei, deg);
  k_scan_a<<<NB_SCAN, 256, 0, stream>>>(deg, rs, bsum);
  k_scan_b<<<1, 256, 0, stream>>>(bsum);
  k_scan_c<<<NB_SCAN, 256, 0, stream>>>(rs, bsum, cursor);
  k_fill<<<(E_TOT+255)/256, 256, 0, stream>>>(ei, cursor, csrc);

  // ---- input split + weight packing ----
  k_split<<<((N_NODESC*HC/4)+255)/256, 256, 0, stream>>>(x, xhi, xlo, N_NODESC*HC/4);
  k_prep_all<<<24, 256, 0, stream>>>(W1l, W1r, W2l, W2r,
                                     w1lhi, w1llo, w1rhi, w1rlo,
                                     w2lhi, w2llo, w2rhi, w2rlo);

  // ---- layer 1 ----
  k_mfma_gemm<8><<<(N_STRIPS+3)/4, 256, 0, stream>>>(xhi, xlo, w1lhi, w1llo,
                                                     w1rhi, w1rlo, xl1b, xr1);
  k_fused1<<<(N_NODESC+3)/4, 256, 0, stream>>>(rs, deg, csrc, xl1b, xr1, att1, b1, hhi, hlo);

  // ---- layer 2 ----
  k_mfma_gemm<4><<<(N_STRIPS+3)/4, 256, 0, stream>>>(hhi, hlo, w2lhi, w2llo,
                                                     w2rhi, w2rlo, xl2b, xr2);
  k_fused2<<<(N_NODESC+3)/4, 256, 0, stream>>>(rs, deg, csrc, xl2b, xr2, att2, b2, out);
}

// Round 6
// 271.587 us; speedup vs baseline: 3.0763x; 1.0870x over previous
//
#include <hip/hip_runtime.h>
#include <hip/hip_bf16.h>
#include <math.h>

#define N_NODESC 50000
#define N_EDGESC 500000
#define E_TOT    (N_EDGESC + N_NODESC)   // 550000 (self-loops appended)
#define IN_CH 128
#define HID 32
#define HEADS 4
#define HC (HEADS*HID)    // 128
#define OUT_CH 64
#define NEG_SLOPE 0.2f
#define NB_SCAN 196        // ceil(50000/256)
#define N_STRIPS (N_NODESC/16)   // 3125 exact

typedef unsigned short u16;
typedef __attribute__((ext_vector_type(8))) short short8;   // 8 bf16 (4 VGPRs)
typedef __attribute__((ext_vector_type(4))) float floatx4;  // 4 fp32 acc

// manual bf16 round-to-nearest-even
__device__ __forceinline__ u16 f2bf(float f){
  unsigned u = __float_as_uint(f);
  return (u16)((u + 0x7FFFu + ((u >> 16) & 1u)) >> 16);
}
__device__ __forceinline__ float bf2f(u16 b){ return __uint_as_float(((unsigned)b) << 16); }
__device__ __forceinline__ float bflo(unsigned q){ return __uint_as_float(q << 16); }
__device__ __forceinline__ float bfhi(unsigned q){ return __uint_as_float(q & 0xFFFF0000u); }
__device__ __forceinline__ float lrelu(float v){ return (v > 0.f) ? v : NEG_SLOPE*v; }

__device__ __forceinline__ void edge_sd(const int* __restrict__ ei, int e, int& s, int& d){
  if (e < N_EDGESC){ s = ei[e]; d = ei[N_EDGESC + e]; }
  else { s = e - N_EDGESC; d = s; }
}

// ---------------- CSR build ----------------
__global__ void k_zero_deg(int* __restrict__ deg){
  int i = blockIdx.x*blockDim.x + threadIdx.x;
  if (i < N_NODESC) deg[i] = 0;
}

__global__ void k_hist(const int* __restrict__ ei, int* __restrict__ deg){
  int e = blockIdx.x*blockDim.x + threadIdx.x;
  if (e >= E_TOT) return;
  int s, d; edge_sd(ei, e, s, d);
  atomicAdd(&deg[d], 1);
}

__global__ void k_scan_a(const int* __restrict__ deg, int* __restrict__ rs,
                         int* __restrict__ bsum){
  __shared__ int sh[256];
  int i = blockIdx.x*256 + threadIdx.x;
  int v = (i < N_NODESC) ? deg[i] : 0;
  sh[threadIdx.x] = v;
  __syncthreads();
  for (int off=1; off<256; off<<=1){
    int t = (threadIdx.x >= off) ? sh[threadIdx.x-off] : 0;
    __syncthreads();
    sh[threadIdx.x] += t;
    __syncthreads();
  }
  if (i < N_NODESC) rs[i] = sh[threadIdx.x] - v;
  if (threadIdx.x == 255) bsum[blockIdx.x] = sh[255];
}

__global__ void k_scan_b(int* __restrict__ bsum){
  __shared__ int sh[256];
  int v = (threadIdx.x < NB_SCAN) ? bsum[threadIdx.x] : 0;
  sh[threadIdx.x] = v;
  __syncthreads();
  for (int off=1; off<256; off<<=1){
    int t = (threadIdx.x >= off) ? sh[threadIdx.x-off] : 0;
    __syncthreads();
    sh[threadIdx.x] += t;
    __syncthreads();
  }
  if (threadIdx.x < NB_SCAN) bsum[threadIdx.x] = sh[threadIdx.x] - v;
}

__global__ void k_scan_c(int* __restrict__ rs, const int* __restrict__ bsum,
                         int* __restrict__ cursor){
  int i = blockIdx.x*256 + threadIdx.x;
  if (i >= N_NODESC) return;
  int v = rs[i] + bsum[blockIdx.x];
  rs[i] = v;
  cursor[i] = v;
}

__global__ void k_fill(const int* __restrict__ ei, int* __restrict__ cursor,
                       int* __restrict__ csrc){
  int e = blockIdx.x*blockDim.x + threadIdx.x;
  if (e >= E_TOT) return;
  int s, d; edge_sd(ei, e, s, d);
  int pos = atomicAdd(&cursor[d], 1);
  csrc[pos] = s;
}

// ---------------- split x into bf16 hi/lo (A operand for gemm1) ----------------
__global__ void k_split(const float* __restrict__ X, u16* __restrict__ hi,
                        u16* __restrict__ lo, int total4){
  int i = blockIdx.x*blockDim.x + threadIdx.x;
  if (i >= total4) return;
  float4 v = ((const float4*)X)[i];
  ushort4 h, l;
  h.x = f2bf(v.x); l.x = f2bf(v.x - bf2f(h.x));
  h.y = f2bf(v.y); l.y = f2bf(v.y - bf2f(h.y));
  h.z = f2bf(v.z); l.z = f2bf(v.z - bf2f(h.z));
  h.w = f2bf(v.w); l.w = f2bf(v.w - bf2f(h.w));
  ((ushort4*)hi)[i] = h;
  ((ushort4*)lo)[i] = l;
}

// ---------------- weight prep (bf16 hi only) ----------------
// packed idx = (((c*4 + t)*64) + lane)*8 + j
// value      = W[(t*32 + (lane>>4)*8 + j)*N + c*16 + (lane&15)]
__global__ void k_prep_all(const float* __restrict__ W1l, const float* __restrict__ W1r,
                           const float* __restrict__ W2l, const float* __restrict__ W2r,
                           u16* __restrict__ w1lh, u16* __restrict__ w1rh,
                           u16* __restrict__ w2lh, u16* __restrict__ w2rh){
  int b = blockIdx.x;
  const float* W; u16 *Th; int N, base;
  if (b < 8)      { W=W1l; Th=w1lh; N=HC;     base=b;    }
  else if (b < 16){ W=W1r; Th=w1rh; N=HC;     base=b-8;  }
  else if (b < 20){ W=W2l; Th=w2lh; N=OUT_CH; base=b-16; }
  else            { W=W2r; Th=w2rh; N=OUT_CH; base=b-20; }
  int tid = base*256 + threadIdx.x;
  int lane = tid & 63;
  int t = (tid >> 6) & 3;
  int c = tid >> 8;
  int k0 = t*32 + (lane>>4)*8;
  int n  = c*16 + (lane&15);
  #pragma unroll
  for (int j=0;j<8;j++){
    Th[(size_t)tid*8 + j] = f2bf(W[(size_t)(k0+j)*N + n]);
  }
}

// ---------------- register-B MFMA GEMM ----------------
// Block = 4 waves. Waves 0,1 compute A@Wl -> bf16 table Olb; waves 2,3 compute
// A@Wr -> fp32 Or. Each wave owns NCW column-tiles of B held in VGPRs for the
// whole block (SPB strips); A (hi/lo bf16) double-buffered in registers.
// NCW=4 -> layer1 (N=128 per matrix); NCW=2 -> layer2 (N=64).
template<int NCW, int SPB>
__launch_bounds__(256, 2)
__global__ void k_gemm_regB(const u16* __restrict__ Ahi, const u16* __restrict__ Alo,
                            const u16* __restrict__ BlT, const u16* __restrict__ BrT,
                            u16* __restrict__ Olb, float* __restrict__ Or){
  constexpr int NLD = 2*NCW*16;        // output leading dim (= N of each matrix)
  int wave = threadIdx.x >> 6, lane = threadIdx.x & 63;
  int m = lane & 15, quad = lane >> 4;
  bool isl = (wave < 2);
  int ctbase = (isl ? wave : wave - 2) * NCW;
  const u16* __restrict__ BT = isl ? BlT : BrT;

  // B into registers: NCW ct x 4 k-tiles
  short8 breg[NCW][4];
  #pragma unroll
  for (int c=0;c<NCW;c++)
    #pragma unroll
    for (int t=0;t<4;t++)
      breg[c][t] = *(const short8*)(BT + ((size_t)(((ctbase+c)*4 + t)*64) + lane)*8);

  int strip0 = blockIdx.x * SPB;
  short8 ah[2][4], al[2][4];

  // prime buffer 0
  {
    const u16* p1 = Ahi + (size_t)(strip0*16 + m)*128 + quad*8;
    const u16* p2 = Alo + (size_t)(strip0*16 + m)*128 + quad*8;
    #pragma unroll
    for (int t=0;t<4;t++){
      ah[0][t] = *(const short8*)(p1 + t*32);
      al[0][t] = *(const short8*)(p2 + t*32);
    }
  }

  #pragma unroll
  for (int i=0;i<SPB;i++){
    int s = strip0 + i;
    if (s >= N_STRIPS) break;
    if (i+1 < SPB && s+1 < N_STRIPS){
      const u16* p1 = Ahi + (size_t)((s+1)*16 + m)*128 + quad*8;
      const u16* p2 = Alo + (size_t)((s+1)*16 + m)*128 + quad*8;
      #pragma unroll
      for (int t=0;t<4;t++){
        ah[(i+1)&1][t] = *(const short8*)(p1 + t*32);
        al[(i+1)&1][t] = *(const short8*)(p2 + t*32);
      }
    }
    const int b = i&1;
    floatx4 acc[NCW];
    #pragma unroll
    for (int c=0;c<NCW;c++) acc[c] = (floatx4){0.f,0.f,0.f,0.f};
    #pragma unroll
    for (int t=0;t<4;t++){
      #pragma unroll
      for (int c=0;c<NCW;c++){
        acc[c] = __builtin_amdgcn_mfma_f32_16x16x32_bf16(ah[b][t], breg[c][t], acc[c], 0,0,0);
        acc[c] = __builtin_amdgcn_mfma_f32_16x16x32_bf16(al[b][t], breg[c][t], acc[c], 0,0,0);
      }
    }
    int row0 = s*16;
    if (isl){
      #pragma unroll
      for (int c=0;c<NCW;c++)
        #pragma unroll
        for (int r=0;r<4;r++)
          Olb[(size_t)(row0 + quad*4 + r)*NLD + (ctbase+c)*16 + m] = f2bf(acc[c][r]);
    } else {
      #pragma unroll
      for (int c=0;c<NCW;c++)
        #pragma unroll
        for (int r=0;r<4;r++)
          Or[(size_t)(row0 + quad*4 + r)*NLD + (ctbase+c)*16 + m] = acc[c][r];
    }
  }
}

// ---------------- layer 1 fused: per-dst softmax aggregate + bias + ELU ----------------
// wave per destination; lane holds channels {2l,2l+1} (same head, HID=32).
// xlb: bf16 gather table [N x 128]. No max-subtraction (scores O(5), exp safe;
// alpha invariant to per-dst constants) -> iterations independent, 4-way unrolled.
__global__ void k_fused1(const int* __restrict__ rs, const int* __restrict__ deg,
                         const int* __restrict__ csrc, const u16* __restrict__ xlb,
                         const float* __restrict__ xr, const float* __restrict__ att,
                         const float* __restrict__ b1,
                         u16* __restrict__ Hhi, u16* __restrict__ Hlo){
  int wave = threadIdx.x >> 6;
  int lane = threadIdx.x & 63;
  int d = blockIdx.x*4 + wave;
  if (d >= N_NODESC) return;

  float2 xrv = ((const float2*)(xr + (size_t)d*HC))[lane];
  float2 atv = ((const float2*)att)[lane];
  float2 bv  = ((const float2*)b1)[lane];

  int start = rs[d];
  int degd  = deg[d];
  const unsigned* __restrict__ xt = (const unsigned*)xlb;  // [N x 64] uints

  float lden = 0.f;
  float2 acc = {0.f, 0.f};

  int i = 0;
  int s0=0,s1=0,s2=0,s3=0;
  if (degd >= 4){
    s0 = csrc[start+0]; s1 = csrc[start+1]; s2 = csrc[start+2]; s3 = csrc[start+3];
  }
  for (; i + 4 <= degd; ){
    int t0=s0, t1=s1, t2=s2, t3=s3;
    int ni = i + 4;
    if (ni + 4 <= degd){
      s0 = csrc[start+ni+0]; s1 = csrc[start+ni+1];
      s2 = csrc[start+ni+2]; s3 = csrc[start+ni+3];
    }
    unsigned q0 = xt[(size_t)t0*64 + lane];
    unsigned q1 = xt[(size_t)t1*64 + lane];
    unsigned q2 = xt[(size_t)t2*64 + lane];
    unsigned q3 = xt[(size_t)t3*64 + lane];

    float sc0 = lrelu(bflo(q0)+xrv.x)*atv.x + lrelu(bfhi(q0)+xrv.y)*atv.y;
    float sc1 = lrelu(bflo(q1)+xrv.x)*atv.x + lrelu(bfhi(q1)+xrv.y)*atv.y;
    float sc2 = lrelu(bflo(q2)+xrv.x)*atv.x + lrelu(bfhi(q2)+xrv.y)*atv.y;
    float sc3 = lrelu(bflo(q3)+xrv.x)*atv.x + lrelu(bfhi(q3)+xrv.y)*atv.y;
    #pragma unroll
    for (int off=1; off<16; off<<=1){
      sc0 += __shfl_xor(sc0, off);
      sc1 += __shfl_xor(sc1, off);
      sc2 += __shfl_xor(sc2, off);
      sc3 += __shfl_xor(sc3, off);
    }
    float p0 = __expf(sc0), p1 = __expf(sc1), p2 = __expf(sc2), p3 = __expf(sc3);
    lden += (p0+p1) + (p2+p3);
    acc.x += p0*bflo(q0) + p1*bflo(q1) + p2*bflo(q2) + p3*bflo(q3);
    acc.y += p0*bfhi(q0) + p1*bfhi(q1) + p2*bfhi(q2) + p3*bfhi(q3);
    i = ni;
  }
  for (; i < degd; i++){
    int s = csrc[start+i];
    unsigned q = xt[(size_t)s*64 + lane];
    float sc = lrelu(bflo(q)+xrv.x)*atv.x + lrelu(bfhi(q)+xrv.y)*atv.y;
    #pragma unroll
    for (int off=1; off<16; off<<=1) sc += __shfl_xor(sc, off);
    float p = __expf(sc);
    lden += p;
    acc.x += p*bflo(q);
    acc.y += p*bfhi(q);
  }

  float inv = 1.f / (lden + 1e-16f);
  float ox = acc.x*inv + bv.x;
  float oy = acc.y*inv + bv.y;
  ox = (ox > 0.f) ? ox : (__expf(ox) - 1.f);
  oy = (oy > 0.f) ? oy : (__expf(oy) - 1.f);

  u16 hx = f2bf(ox), hy = f2bf(oy);
  ushort2 hh; hh.x = hx; hh.y = hy;
  ushort2 hl; hl.x = f2bf(ox - bf2f(hx)); hl.y = f2bf(oy - bf2f(hy));
  ((ushort2*)(Hhi + (size_t)d*HC))[lane] = hh;
  ((ushort2*)(Hlo + (size_t)d*HC))[lane] = hl;
}

// ---------------- layer 2 fused: per-dst softmax aggregate + bias ----------------
__global__ void k_fused2(const int* __restrict__ rs, const int* __restrict__ deg,
                         const int* __restrict__ csrc, const u16* __restrict__ xlb,
                         const float* __restrict__ xr, const float* __restrict__ att,
                         const float* __restrict__ b2, float* __restrict__ out){
  int wave = threadIdx.x >> 6;
  int lane = threadIdx.x & 63;
  int d = blockIdx.x*4 + wave;
  if (d >= N_NODESC) return;

  float xrv = xr[(size_t)d*OUT_CH + lane];
  float atv = att[lane];
  float bv  = b2[lane];

  int start = rs[d];
  int degd  = deg[d];

  float lden = 0.f, acc = 0.f;

  int i = 0;
  int s0=0,s1=0,s2=0,s3=0;
  if (degd >= 4){
    s0 = csrc[start+0]; s1 = csrc[start+1]; s2 = csrc[start+2]; s3 = csrc[start+3];
  }
  for (; i + 4 <= degd; ){
    int t0=s0, t1=s1, t2=s2, t3=s3;
    int ni = i + 4;
    if (ni + 4 <= degd){
      s0 = csrc[start+ni+0]; s1 = csrc[start+ni+1];
      s2 = csrc[start+ni+2]; s3 = csrc[start+ni+3];
    }
    float x0 = bf2f(xlb[(size_t)t0*OUT_CH + lane]);
    float x1 = bf2f(xlb[(size_t)t1*OUT_CH + lane]);
    float x2 = bf2f(xlb[(size_t)t2*OUT_CH + lane]);
    float x3 = bf2f(xlb[(size_t)t3*OUT_CH + lane]);

    float sc0 = lrelu(x0+xrv)*atv;
    float sc1 = lrelu(x1+xrv)*atv;
    float sc2 = lrelu(x2+xrv)*atv;
    float sc3 = lrelu(x3+xrv)*atv;
    #pragma unroll
    for (int off=1; off<64; off<<=1){
      sc0 += __shfl_xor(sc0, off);
      sc1 += __shfl_xor(sc1, off);
      sc2 += __shfl_xor(sc2, off);
      sc3 += __shfl_xor(sc3, off);
    }
    float p0 = __expf(sc0), p1 = __expf(sc1), p2 = __expf(sc2), p3 = __expf(sc3);
    lden += (p0+p1) + (p2+p3);
    acc += p0*x0 + p1*x1 + p2*x2 + p3*x3;
    i = ni;
  }
  for (; i < degd; i++){
    int s = csrc[start+i];
    float xv = bf2f(xlb[(size_t)s*OUT_CH + lane]);
    float sc = lrelu(xv+xrv)*atv;
    #pragma unroll
    for (int off=1; off<64; off<<=1) sc += __shfl_xor(sc, off);
    float p = __expf(sc);
    lden += p;
    acc  += p*xv;
  }
  out[(size_t)d*OUT_CH + lane] = acc / (lden + 1e-16f) + bv;
}

extern "C" void kernel_launch(void* const* d_in, const int* in_sizes, int n_in,
                              void* d_out, int out_size, void* d_ws, size_t ws_size,
                              hipStream_t stream) {
  const float* x    = (const float*)d_in[0];
  const int*   ei   = (const int*)d_in[1];
  const float* W1l  = (const float*)d_in[2];
  const float* W1r  = (const float*)d_in[3];
  const float* att1 = (const float*)d_in[4];
  const float* b1   = (const float*)d_in[5];
  const float* W2l  = (const float*)d_in[6];
  const float* W2r  = (const float*)d_in[7];
  const float* att2 = (const float*)d_in[8];
  const float* b2   = (const float*)d_in[9];
  float* out = (float*)d_out;

  // workspace layout (units of float; offsets multiples of 4 -> 16B aligned)
  float* ws = (float*)d_ws;
  size_t off = 0;
  float* xr1 = ws + off; off += (size_t)N_NODESC*HC;          // fp32 [N x 128]
  float* xr2 = ws + off; off += (size_t)N_NODESC*OUT_CH;      // fp32 [N x 64]
  u16* xl1b = (u16*)(ws + off); off += (size_t)N_NODESC*HC/2;     // bf16 gather [N x 128]
  u16* xl2b = (u16*)(ws + off); off += (size_t)N_NODESC*OUT_CH/2; // bf16 gather [N x 64]
  u16* xhi = (u16*)(ws + off); off += (size_t)N_NODESC*HC/2;  // A for gemm1
  u16* xlo = (u16*)(ws + off); off += (size_t)N_NODESC*HC/2;
  u16* hhi = (u16*)(ws + off); off += (size_t)N_NODESC*HC/2;  // A for gemm2
  u16* hlo = (u16*)(ws + off); off += (size_t)N_NODESC*HC/2;
  u16* w1lh = (u16*)(ws + off); off += IN_CH*HC/2;
  u16* w1rh = (u16*)(ws + off); off += IN_CH*HC/2;
  u16* w2lh = (u16*)(ws + off); off += HC*OUT_CH/2;
  u16* w2rh = (u16*)(ws + off); off += HC*OUT_CH/2;
  int* deg    = (int*)(ws + off); off += N_NODESC;
  int* rs     = (int*)(ws + off); off += N_NODESC;
  int* cursor = (int*)(ws + off); off += N_NODESC;
  int* bsum   = (int*)(ws + off); off += 256;
  int* csrc   = (int*)(ws + off); off += E_TOT;

  // ---- CSR build (graph identical for both layers) ----
  k_zero_deg<<<(N_NODESC+255)/256, 256, 0, stream>>>(deg);
  k_hist<<<(E_TOT+255)/256, 256, 0, stream>>>(ei, deg);
  k_scan_a<<<NB_SCAN, 256, 0, stream>>>(deg, rs, bsum);
  k_scan_b<<<1, 256, 0, stream>>>(bsum);
  k_scan_c<<<NB_SCAN, 256, 0, stream>>>(rs, bsum, cursor);
  k_fill<<<(E_TOT+255)/256, 256, 0, stream>>>(ei, cursor, csrc);

  // ---- input split + weight packing ----
  k_split<<<((N_NODESC*HC/4)+255)/256, 256, 0, stream>>>(x, xhi, xlo, N_NODESC*HC/4);
  k_prep_all<<<24, 256, 0, stream>>>(W1l, W1r, W2l, W2r, w1lh, w1rh, w2lh, w2rh);

  const int NB_G = (N_STRIPS + 3)/4;   // SPB=4
  // ---- layer 1 ----
  k_gemm_regB<4,4><<<NB_G, 256, 0, stream>>>(xhi, xlo, w1lh, w1rh, xl1b, xr1);
  k_fused1<<<(N_NODESC+3)/4, 256, 0, stream>>>(rs, deg, csrc, xl1b, xr1, att1, b1, hhi, hlo);

  // ---- layer 2 ----
  k_gemm_regB<2,4><<<NB_G, 256, 0, stream>>>(hhi, hlo, w2lh, w2rh, xl2b, xr2);
  k_fused2<<<(N_NODESC+3)/4, 256, 0, stream>>>(rs, deg, csrc, xl2b, xr2, att2, b2, out);
}

// Round 7
// 262.736 us; speedup vs baseline: 3.1799x; 1.0337x over previous
//
#include <hip/hip_runtime.h>
#include <hip/hip_bf16.h>
#include <math.h>

#define N_NODESC 50000
#define N_EDGESC 500000
#define E_TOT    (N_EDGESC + N_NODESC)   // 550000 (self-loops appended)
#define IN_CH 128
#define HID 32
#define HEADS 4
#define HC (HEADS*HID)    // 128
#define OUT_CH 64
#define NEG_SLOPE 0.2f
#define NB_SCAN 196        // ceil(50000/256)
#define N_STRIPS (N_NODESC/16)   // 3125 exact

typedef unsigned short u16;
typedef __attribute__((ext_vector_type(8))) short short8;        // 8 bf16 (4 VGPRs)
typedef __attribute__((ext_vector_type(8))) unsigned short ushort8v;
typedef __attribute__((ext_vector_type(4))) unsigned short ushort4v;
typedef __attribute__((ext_vector_type(4))) float floatx4;       // 4 fp32 acc

// manual bf16 round-to-nearest-even
__device__ __forceinline__ u16 f2bf(float f){
  unsigned u = __float_as_uint(f);
  return (u16)((u + 0x7FFFu + ((u >> 16) & 1u)) >> 16);
}
__device__ __forceinline__ float bf2f(u16 b){ return __uint_as_float(((unsigned)b) << 16); }
__device__ __forceinline__ float lrelu(float v){ return (v > 0.f) ? v : NEG_SLOPE*v; }

__device__ __forceinline__ void edge_sd(const int* __restrict__ ei, int e, int& s, int& d){
  if (e < N_EDGESC){ s = ei[e]; d = ei[N_EDGESC + e]; }
  else { s = e - N_EDGESC; d = s; }
}

// ---------------- CSR build ----------------
__global__ void k_zero_deg(int* __restrict__ deg){
  int i = blockIdx.x*blockDim.x + threadIdx.x;
  if (i < N_NODESC) deg[i] = 0;
}

__global__ void k_hist(const int* __restrict__ ei, int* __restrict__ deg){
  int e = blockIdx.x*blockDim.x + threadIdx.x;
  if (e >= E_TOT) return;
  int s, d; edge_sd(ei, e, s, d);
  atomicAdd(&deg[d], 1);
}

__global__ void k_scan_a(const int* __restrict__ deg, int* __restrict__ rs,
                         int* __restrict__ bsum){
  __shared__ int sh[256];
  int i = blockIdx.x*256 + threadIdx.x;
  int v = (i < N_NODESC) ? deg[i] : 0;
  sh[threadIdx.x] = v;
  __syncthreads();
  for (int off=1; off<256; off<<=1){
    int t = (threadIdx.x >= off) ? sh[threadIdx.x-off] : 0;
    __syncthreads();
    sh[threadIdx.x] += t;
    __syncthreads();
  }
  if (i < N_NODESC) rs[i] = sh[threadIdx.x] - v;
  if (threadIdx.x == 255) bsum[blockIdx.x] = sh[255];
}

__global__ void k_scan_b(int* __restrict__ bsum){
  __shared__ int sh[256];
  int v = (threadIdx.x < NB_SCAN) ? bsum[threadIdx.x] : 0;
  sh[threadIdx.x] = v;
  __syncthreads();
  for (int off=1; off<256; off<<=1){
    int t = (threadIdx.x >= off) ? sh[threadIdx.x-off] : 0;
    __syncthreads();
    sh[threadIdx.x] += t;
    __syncthreads();
  }
  if (threadIdx.x < NB_SCAN) bsum[threadIdx.x] = sh[threadIdx.x] - v;
}

__global__ void k_scan_c(int* __restrict__ rs, const int* __restrict__ bsum,
                         int* __restrict__ cursor){
  int i = blockIdx.x*256 + threadIdx.x;
  if (i >= N_NODESC) return;
  int v = rs[i] + bsum[blockIdx.x];
  rs[i] = v;
  cursor[i] = v;
}

__global__ void k_fill(const int* __restrict__ ei, int* __restrict__ cursor,
                       int* __restrict__ csrc){
  int e = blockIdx.x*blockDim.x + threadIdx.x;
  if (e >= E_TOT) return;
  int s, d; edge_sd(ei, e, s, d);
  int pos = atomicAdd(&cursor[d], 1);
  csrc[pos] = s;
}

// ---------------- split x into bf16 hi/lo (A operand for gemm1) ----------------
__global__ void k_split(const float* __restrict__ X, u16* __restrict__ hi,
                        u16* __restrict__ lo, int total4){
  int i = blockIdx.x*blockDim.x + threadIdx.x;
  if (i >= total4) return;
  float4 v = ((const float4*)X)[i];
  ushort4 h, l;
  h.x = f2bf(v.x); l.x = f2bf(v.x - bf2f(h.x));
  h.y = f2bf(v.y); l.y = f2bf(v.y - bf2f(h.y));
  h.z = f2bf(v.z); l.z = f2bf(v.z - bf2f(h.z));
  h.w = f2bf(v.w); l.w = f2bf(v.w - bf2f(h.w));
  ((ushort4*)hi)[i] = h;
  ((ushort4*)lo)[i] = l;
}

// ---------------- weight prep (bf16 hi only) ----------------
// packed idx = (((c*4 + t)*64) + lane)*8 + j
// value      = W[(t*32 + (lane>>4)*8 + j)*N + c*16 + (lane&15)]
__global__ void k_prep_all(const float* __restrict__ W1l, const float* __restrict__ W1r,
                           const float* __restrict__ W2l, const float* __restrict__ W2r,
                           u16* __restrict__ w1lh, u16* __restrict__ w1rh,
                           u16* __restrict__ w2lh, u16* __restrict__ w2rh){
  int b = blockIdx.x;
  const float* W; u16 *Th; int N, base;
  if (b < 8)      { W=W1l; Th=w1lh; N=HC;     base=b;    }
  else if (b < 16){ W=W1r; Th=w1rh; N=HC;     base=b-8;  }
  else if (b < 20){ W=W2l; Th=w2lh; N=OUT_CH; base=b-16; }
  else            { W=W2r; Th=w2rh; N=OUT_CH; base=b-20; }
  int tid = base*256 + threadIdx.x;
  int lane = tid & 63;
  int t = (tid >> 6) & 3;
  int c = tid >> 8;
  int k0 = t*32 + (lane>>4)*8;
  int n  = c*16 + (lane&15);
  #pragma unroll
  for (int j=0;j<8;j++){
    Th[(size_t)tid*8 + j] = f2bf(W[(size_t)(k0+j)*N + n]);
  }
}

// ---------------- register-B MFMA GEMM ----------------
// Block = 4 waves. Waves 0,1 compute A@Wl -> bf16 table Olb; waves 2,3 compute
// A@Wr -> fp32 Or. Each wave owns NCW column-tiles of B held in VGPRs for the
// whole block (SPB strips); A (hi/lo bf16) double-buffered in registers.
template<int NCW, int SPB>
__launch_bounds__(256, 2)
__global__ void k_gemm_regB(const u16* __restrict__ Ahi, const u16* __restrict__ Alo,
                            const u16* __restrict__ BlT, const u16* __restrict__ BrT,
                            u16* __restrict__ Olb, float* __restrict__ Or){
  constexpr int NLD = 2*NCW*16;        // output leading dim (= N of each matrix)
  int wave = threadIdx.x >> 6, lane = threadIdx.x & 63;
  int m = lane & 15, quad = lane >> 4;
  bool isl = (wave < 2);
  int ctbase = (isl ? wave : wave - 2) * NCW;
  const u16* __restrict__ BT = isl ? BlT : BrT;

  short8 breg[NCW][4];
  #pragma unroll
  for (int c=0;c<NCW;c++)
    #pragma unroll
    for (int t=0;t<4;t++)
      breg[c][t] = *(const short8*)(BT + ((size_t)(((ctbase+c)*4 + t)*64) + lane)*8);

  int strip0 = blockIdx.x * SPB;
  short8 ah[2][4], al[2][4];

  {
    const u16* p1 = Ahi + (size_t)(strip0*16 + m)*128 + quad*8;
    const u16* p2 = Alo + (size_t)(strip0*16 + m)*128 + quad*8;
    #pragma unroll
    for (int t=0;t<4;t++){
      ah[0][t] = *(const short8*)(p1 + t*32);
      al[0][t] = *(const short8*)(p2 + t*32);
    }
  }

  #pragma unroll
  for (int i=0;i<SPB;i++){
    int s = strip0 + i;
    if (s >= N_STRIPS) break;
    if (i+1 < SPB && s+1 < N_STRIPS){
      const u16* p1 = Ahi + (size_t)((s+1)*16 + m)*128 + quad*8;
      const u16* p2 = Alo + (size_t)((s+1)*16 + m)*128 + quad*8;
      #pragma unroll
      for (int t=0;t<4;t++){
        ah[(i+1)&1][t] = *(const short8*)(p1 + t*32);
        al[(i+1)&1][t] = *(const short8*)(p2 + t*32);
      }
    }
    const int b = i&1;
    floatx4 acc[NCW];
    #pragma unroll
    for (int c=0;c<NCW;c++) acc[c] = (floatx4){0.f,0.f,0.f,0.f};
    #pragma unroll
    for (int t=0;t<4;t++){
      #pragma unroll
      for (int c=0;c<NCW;c++){
        acc[c] = __builtin_amdgcn_mfma_f32_16x16x32_bf16(ah[b][t], breg[c][t], acc[c], 0,0,0);
        acc[c] = __builtin_amdgcn_mfma_f32_16x16x32_bf16(al[b][t], breg[c][t], acc[c], 0,0,0);
      }
    }
    int row0 = s*16;
    if (isl){
      #pragma unroll
      for (int c=0;c<NCW;c++)
        #pragma unroll
        for (int r=0;r<4;r++)
          Olb[(size_t)(row0 + quad*4 + r)*NLD + (ctbase+c)*16 + m] = f2bf(acc[c][r]);
    } else {
      #pragma unroll
      for (int c=0;c<NCW;c++)
        #pragma unroll
        for (int r=0;r<4;r++)
          Or[(size_t)(row0 + quad*4 + r)*NLD + (ctbase+c)*16 + m] = acc[c][r];
    }
  }
}

// ---------------- layer 1 fused (v2): 4 groups x 16 lanes, one edge per group --------
// Wave per dst. Group g (lanes 16g..16g+15) processes edge i+g. Lane l (=lane&15)
// covers channels 8l..8l+7 (head = l>>2). Per-head score reduced in 2 shfl stages
// (4-lane span); cross-group combine once at the end. No max-subtraction
// (scores O(5), exp safe; alpha invariant to per-dst constants).
__global__ void k_fused1(const int* __restrict__ rs, const int* __restrict__ deg,
                         const int* __restrict__ csrc, const u16* __restrict__ xlb,
                         const float* __restrict__ xr, const float* __restrict__ att,
                         const float* __restrict__ b1,
                         u16* __restrict__ Hhi, u16* __restrict__ Hlo){
  int wave = threadIdx.x >> 6;
  int lane = threadIdx.x & 63;
  int d = blockIdx.x*4 + wave;
  if (d >= N_NODESC) return;
  int g = lane >> 4;        // edge slot
  int l = lane & 15;        // channel slice: 8l..8l+7

  float xrv[8], atv[8], bv[8];
  const float* xrp = xr + (size_t)d*HC + 8*l;
  #pragma unroll
  for (int j=0;j<8;j++){ xrv[j] = xrp[j]; atv[j] = att[8*l+j]; bv[j] = b1[8*l+j]; }

  int start = rs[d], degd = deg[d];

  float acc[8];
  #pragma unroll
  for (int j=0;j<8;j++) acc[j] = 0.f;
  float den = 0.f;

  int e0 = g;
  int s_cur = csrc[start + ((e0 < degd) ? e0 : 0)];
  for (int i = 0; i < degd; i += 4){
    bool valid = (i + g < degd);
    int s = s_cur;
    int en = i + 4 + g;
    s_cur = csrc[start + ((en < degd) ? en : 0)];   // prefetch next iter
    ushort8v q = *(const ushort8v*)(xlb + (size_t)s*HC + 8*l);  // 16B gather
    float xv[8];
    float sc = 0.f;
    #pragma unroll
    for (int j=0;j<8;j++){
      xv[j] = bf2f(q[j]);
      sc += lrelu(xv[j] + xrv[j]) * atv[j];
    }
    sc += __shfl_xor(sc, 1);
    sc += __shfl_xor(sc, 2);          // per-head sum (4-lane span)
    float p = valid ? __expf(sc) : 0.f;
    den += p;
    #pragma unroll
    for (int j=0;j<8;j++) acc[j] += p * xv[j];
  }
  // cross-group combine
  #pragma unroll
  for (int j=0;j<8;j++){
    acc[j] += __shfl_xor(acc[j], 16);
    acc[j] += __shfl_xor(acc[j], 32);
  }
  den += __shfl_xor(den, 16);
  den += __shfl_xor(den, 32);

  if (g == 0){
    float inv = 1.f / (den + 1e-16f);
    ushort8v oh, ol;
    #pragma unroll
    for (int j=0;j<8;j++){
      float o = acc[j]*inv + bv[j];
      o = (o > 0.f) ? o : (__expf(o) - 1.f);
      u16 h = f2bf(o);
      oh[j] = h;
      ol[j] = f2bf(o - bf2f(h));
    }
    *(ushort8v*)(Hhi + (size_t)d*HC + 8*l) = oh;
    *(ushort8v*)(Hlo + (size_t)d*HC + 8*l) = ol;
  }
}

// ---------------- layer 2 fused (v2): 4 groups x 16 lanes, one edge per group --------
// Lane l covers channels 4l..4l+3; score reduced over 16 lanes (4 shfl stages);
// cross-group combine at end; heads=1.
__global__ void k_fused2(const int* __restrict__ rs, const int* __restrict__ deg,
                         const int* __restrict__ csrc, const u16* __restrict__ xlb,
                         const float* __restrict__ xr, const float* __restrict__ att,
                         const float* __restrict__ b2, float* __restrict__ out){
  int wave = threadIdx.x >> 6;
  int lane = threadIdx.x & 63;
  int d = blockIdx.x*4 + wave;
  if (d >= N_NODESC) return;
  int g = lane >> 4;
  int l = lane & 15;        // channels 4l..4l+3

  float xrv[4], atv[4], bv[4];
  const float* xrp = xr + (size_t)d*OUT_CH + 4*l;
  #pragma unroll
  for (int j=0;j<4;j++){ xrv[j] = xrp[j]; atv[j] = att[4*l+j]; bv[j] = b2[4*l+j]; }

  int start = rs[d], degd = deg[d];

  float acc[4] = {0.f,0.f,0.f,0.f};
  float den = 0.f;

  int e0 = g;
  int s_cur = csrc[start + ((e0 < degd) ? e0 : 0)];
  for (int i = 0; i < degd; i += 4){
    bool valid = (i + g < degd);
    int s = s_cur;
    int en = i + 4 + g;
    s_cur = csrc[start + ((en < degd) ? en : 0)];
    ushort4v q = *(const ushort4v*)(xlb + (size_t)s*OUT_CH + 4*l);  // 8B gather
    float xv[4];
    float sc = 0.f;
    #pragma unroll
    for (int j=0;j<4;j++){
      xv[j] = bf2f(q[j]);
      sc += lrelu(xv[j] + xrv[j]) * atv[j];
    }
    sc += __shfl_xor(sc, 1);
    sc += __shfl_xor(sc, 2);
    sc += __shfl_xor(sc, 4);
    sc += __shfl_xor(sc, 8);          // 16-lane (full-channel) sum
    float p = valid ? __expf(sc) : 0.f;
    den += p;
    #pragma unroll
    for (int j=0;j<4;j++) acc[j] += p * xv[j];
  }
  #pragma unroll
  for (int j=0;j<4;j++){
    acc[j] += __shfl_xor(acc[j], 16);
    acc[j] += __shfl_xor(acc[j], 32);
  }
  den += __shfl_xor(den, 16);
  den += __shfl_xor(den, 32);

  if (g == 0){
    float inv = 1.f / (den + 1e-16f);
    float4 o;
    o.x = acc[0]*inv + bv[0];
    o.y = acc[1]*inv + bv[1];
    o.z = acc[2]*inv + bv[2];
    o.w = acc[3]*inv + bv[3];
    *(float4*)(out + (size_t)d*OUT_CH + 4*l) = o;
  }
}

extern "C" void kernel_launch(void* const* d_in, const int* in_sizes, int n_in,
                              void* d_out, int out_size, void* d_ws, size_t ws_size,
                              hipStream_t stream) {
  const float* x    = (const float*)d_in[0];
  const int*   ei   = (const int*)d_in[1];
  const float* W1l  = (const float*)d_in[2];
  const float* W1r  = (const float*)d_in[3];
  const float* att1 = (const float*)d_in[4];
  const float* b1   = (const float*)d_in[5];
  const float* W2l  = (const float*)d_in[6];
  const float* W2r  = (const float*)d_in[7];
  const float* att2 = (const float*)d_in[8];
  const float* b2   = (const float*)d_in[9];
  float* out = (float*)d_out;

  // workspace layout (units of float; offsets multiples of 4 -> 16B aligned)
  float* ws = (float*)d_ws;
  size_t off = 0;
  float* xr1 = ws + off; off += (size_t)N_NODESC*HC;          // fp32 [N x 128]
  float* xr2 = ws + off; off += (size_t)N_NODESC*OUT_CH;      // fp32 [N x 64]
  u16* xl1b = (u16*)(ws + off); off += (size_t)N_NODESC*HC/2;     // bf16 gather [N x 128]
  u16* xl2b = (u16*)(ws + off); off += (size_t)N_NODESC*OUT_CH/2; // bf16 gather [N x 64]
  u16* xhi = (u16*)(ws + off); off += (size_t)N_NODESC*HC/2;  // A for gemm1
  u16* xlo = (u16*)(ws + off); off += (size_t)N_NODESC*HC/2;
  u16* hhi = (u16*)(ws + off); off += (size_t)N_NODESC*HC/2;  // A for gemm2
  u16* hlo = (u16*)(ws + off); off += (size_t)N_NODESC*HC/2;
  u16* w1lh = (u16*)(ws + off); off += IN_CH*HC/2;
  u16* w1rh = (u16*)(ws + off); off += IN_CH*HC/2;
  u16* w2lh = (u16*)(ws + off); off += HC*OUT_CH/2;
  u16* w2rh = (u16*)(ws + off); off += HC*OUT_CH/2;
  int* deg    = (int*)(ws + off); off += N_NODESC;
  int* rs     = (int*)(ws + off); off += N_NODESC;
  int* cursor = (int*)(ws + off); off += N_NODESC;
  int* bsum   = (int*)(ws + off); off += 256;
  int* csrc   = (int*)(ws + off); off += E_TOT;

  // ---- CSR build (graph identical for both layers) ----
  k_zero_deg<<<(N_NODESC+255)/256, 256, 0, stream>>>(deg);
  k_hist<<<(E_TOT+255)/256, 256, 0, stream>>>(ei, deg);
  k_scan_a<<<NB_SCAN, 256, 0, stream>>>(deg, rs, bsum);
  k_scan_b<<<1, 256, 0, stream>>>(bsum);
  k_scan_c<<<NB_SCAN, 256, 0, stream>>>(rs, bsum, cursor);
  k_fill<<<(E_TOT+255)/256, 256, 0, stream>>>(ei, cursor, csrc);

  // ---- input split + weight packing ----
  k_split<<<((N_NODESC*HC/4)+255)/256, 256, 0, stream>>>(x, xhi, xlo, N_NODESC*HC/4);
  k_prep_all<<<24, 256, 0, stream>>>(W1l, W1r, W2l, W2r, w1lh, w1rh, w2lh, w2rh);

  const int NB_G = (N_STRIPS + 3)/4;   // SPB=4
  // ---- layer 1 ----
  k_gemm_regB<4,4><<<NB_G, 256, 0, stream>>>(xhi, xlo, w1lh, w1rh, xl1b, xr1);
  k_fused1<<<(N_NODESC+3)/4, 256, 0, stream>>>(rs, deg, csrc, xl1b, xr1, att1, b1, hhi, hlo);

  // ---- layer 2 ----
  k_gemm_regB<2,4><<<NB_G, 256, 0, stream>>>(hhi, hlo, w2lh, w2rh, xl2b, xr2);
  k_fused2<<<(N_NODESC+3)/4, 256, 0, stream>>>(rs, deg, csrc, xl2b, xr2, att2, b2, out);
}